// Round 10
// baseline (2795.600 us; speedup 1.0000x reference)
//
#include <hip/hip_runtime.h>
#include <cstdint>

typedef __bf16 bf16_t;
typedef __bf16 bf16x8 __attribute__((ext_vector_type(8)));
typedef float  f32x4  __attribute__((ext_vector_type(4)));
typedef unsigned int u32;

#define DEPTH 6
#define HEADS 12
#define DH    64
#define DIM   768
#define MLPD  3072
#define FEAT  1000
#define BATCH 32
#define SEQ   197
#define NP    224          // padded j stride for attention matrices
#define TOK   (BATCH*SEQ)  // 6304
#define ITILES 25          // ceil(197/8)

__device__ __forceinline__ f32x4 zero4() {
    f32x4 z; z[0] = 0.f; z[1] = 0.f; z[2] = 0.f; z[3] = 0.f; return z;
}

__device__ __forceinline__ f32x4 mfma16(bf16x8 a, bf16x8 b, f32x4 c) {
    return __builtin_amdgcn_mfma_f32_16x16x32_bf16(a, b, c, 0, 0, 0);
}

// async global->LDS, 16B per lane. lds base must be wave-uniform; HW adds lane*16.
typedef const __attribute__((address_space(1))) u32* gas_ptr;
typedef __attribute__((address_space(3))) u32*       las_ptr;
__device__ __forceinline__ void gload16(const bf16_t* g, bf16_t* l) {
    __builtin_amdgcn_global_load_lds((gas_ptr)g, (las_ptr)l, 16, 0, 0);
}

// ---------------- concat cls + x -> xbuf ----------------
__global__ __launch_bounds__(256) void concat_k(const float* __restrict__ x,
                                                const float* __restrict__ cls,
                                                float* __restrict__ xbuf) {
    int idx = blockIdx.x * 256 + threadIdx.x;      // exactly 6304*768 threads
    int col = idx % DIM;
    int row = idx / DIM;
    int b = row / SEQ, p = row % SEQ;
    xbuf[idx] = (p == 0) ? cls[col] : x[(b * 196 + p - 1) * DIM + col];
}

// ---------------- transpose + fp32->bf16:  W[K][N] -> Wt[N][K] ----------------
__global__ __launch_bounds__(256) void tcvt_k(const float* __restrict__ W,
                                              bf16_t* __restrict__ Wt,
                                              int K, int N) {
    __shared__ float t[32][33];
    int n0 = blockIdx.x * 32, k0 = blockIdx.y * 32;
    int c = threadIdx.x & 31, r = threadIdx.x >> 5;
#pragma unroll
    for (int i = 0; i < 4; i++) {
        int k = k0 + r + i * 8, n = n0 + c;        // K is always a multiple of 32
        t[r + i * 8][c] = (n < N) ? W[k * N + n] : 0.f;
    }
    __syncthreads();
#pragma unroll
    for (int i = 0; i < 4; i++) {
        int n = n0 + r + i * 8, k = k0 + c;
        if (n < N) Wt[n * K + k] = (bf16_t)t[c][r + i * 8];
    }
}

// ---------------- row LayerNorm over 768 cols, fp32 in -> bf16 out ----------------
__global__ __launch_bounds__(256) void ln_k(const float* __restrict__ x, long row_stride,
                                            const float* __restrict__ g,
                                            const float* __restrict__ b,
                                            bf16_t* __restrict__ out) {
    int row = blockIdx.x;
    const float* xr = x + (long)row * row_stride;
    int t = threadIdx.x;
    float v0 = xr[t], v1 = xr[t + 256], v2 = xr[t + 512];
    float s  = v0 + v1 + v2;
    float sq = v0 * v0 + v1 * v1 + v2 * v2;
#pragma unroll
    for (int o = 1; o < 64; o <<= 1) { s += __shfl_xor(s, o); sq += __shfl_xor(sq, o); }
    __shared__ float ss[4], sqs[4];
    int w = t >> 6;
    if ((t & 63) == 0) { ss[w] = s; sqs[w] = sq; }
    __syncthreads();
    s  = ss[0] + ss[1] + ss[2] + ss[3];
    sq = sqs[0] + sqs[1] + sqs[2] + sqs[3];
    float m  = s * (1.f / 768.f);
    float rs = rsqrtf(sq * (1.f / 768.f) - m * m + 1e-5f);
    bf16_t* orow = out + (long)row * DIM;
    orow[t]       = (bf16_t)((v0 - m) * rs * g[t]       + b[t]);
    orow[t + 256] = (bf16_t)((v1 - m) * rs * g[t + 256] + b[t + 256]);
    orow[t + 512] = (bf16_t)((v2 - m) * rs * g[t + 512] + b[t + 512]);
}

// ============ big GEMM: r3 structure (best measured) + split-K via blockIdx.z ============
// 128x128 tile, BK=32, 4 waves, 2-buf double-buffered, gload16 staging, __syncthreads.
// MODE 0: Cb=acc; 1: Cf+=acc+bias; 2: Cb=gelu(acc+bias); 3: Cf[kc*M*N+..]=acc (split-K)
template <int MODE>
__global__ __launch_bounds__(256) void gemm_k(const bf16_t* __restrict__ A,
                                              const bf16_t* __restrict__ Bt,
                                              const float* __restrict__ bias,
                                              float* __restrict__ Cf,
                                              bf16_t* __restrict__ Cb,
                                              int M, int N, int Kstride, int Klen) {
    __shared__ bf16_t sA[2][128][32];
    __shared__ bf16_t sB[2][128][32];
    int tid = threadIdx.x;
    int bm = blockIdx.x * 128, bn = blockIdx.y * 128;
    long koff = (long)blockIdx.z * Klen;
    int wave = tid >> 6, lane = tid & 63;
    int wm = (wave >> 1) * 64, wn = (wave & 1) * 64;
    int la = lane & 15, lb = lane >> 4;

    int rowA[2], rowB[2], colE[2];
#pragma unroll
    for (int q = 0; q < 2; q++) {
        int li = (wave * 2 + q) * 64 + lane;
        int row = li >> 2;
        colE[q] = (li & 3) * 8;
        int ar = bm + row; if (ar > M - 1) ar = M - 1;
        int br = bn + row; if (br > N - 1) br = N - 1;
        rowA[q] = ar; rowB[q] = br;
    }

    f32x4 acc[4][4];
#pragma unroll
    for (int m = 0; m < 4; m++)
#pragma unroll
        for (int n = 0; n < 4; n++) acc[m][n] = zero4();

    int nt = Klen >> 5;
#pragma unroll
    for (int q = 0; q < 2; q++) {
        gload16(A  + (long)rowA[q] * Kstride + koff + colE[q], &sA[0][0][0] + (wave * 2 + q) * 512);
        gload16(Bt + (long)rowB[q] * Kstride + koff + colE[q], &sB[0][0][0] + (wave * 2 + q) * 512);
    }
    __syncthreads();
    for (int t = 0; t < nt; t++) {
        int cur = t & 1;
        if (t + 1 < nt) {
            long k0 = koff + ((t + 1) << 5);
#pragma unroll
            for (int q = 0; q < 2; q++) {
                gload16(A  + (long)rowA[q] * Kstride + k0 + colE[q], &sA[cur ^ 1][0][0] + (wave * 2 + q) * 512);
                gload16(Bt + (long)rowB[q] * Kstride + k0 + colE[q], &sB[cur ^ 1][0][0] + (wave * 2 + q) * 512);
            }
        }
        bf16x8 af[4], bfr[4];
#pragma unroll
        for (int m = 0; m < 4; m++) af[m]  = *(const bf16x8*)&sA[cur][wm + m * 16 + la][lb * 8];
#pragma unroll
        for (int n = 0; n < 4; n++) bfr[n] = *(const bf16x8*)&sB[cur][wn + n * 16 + la][lb * 8];
#pragma unroll
        for (int m = 0; m < 4; m++)
#pragma unroll
            for (int n = 0; n < 4; n++)
                acc[m][n] = mfma16(af[m], bfr[n], acc[m][n]);
        __syncthreads();
    }

    long kout = (long)blockIdx.z * M * (long)N;   // split-K output chunk offset
#pragma unroll
    for (int m = 0; m < 4; m++) {
#pragma unroll
        for (int n = 0; n < 4; n++) {
            int ib = bm + wm + m * 16 + lb * 4;
            int jb = bn + wn + n * 16 + la;
            if (jb >= N) continue;
            float bv = (MODE == 1 || MODE == 2) ? bias[jb] : 0.f;
#pragma unroll
            for (int r = 0; r < 4; r++) {
                int i = ib + r;
                if (i >= M) continue;
                float v = acc[m][n][r];
                if (MODE == 0) {
                    Cb[(long)i * N + jb] = (bf16_t)v;
                } else if (MODE == 1) {
                    Cf[(long)i * N + jb] += v + bv;
                } else if (MODE == 2) {
                    float u = v + bv;
                    Cb[(long)i * N + jb] = (bf16_t)(0.5f * u * (1.f + erff(u * 0.70710678118f)));
                } else {
                    Cf[kout + (long)i * N + jb] = v;
                }
            }
        }
    }
}

// ---------------- split-K reduce: xbuf += p0 + p1 + bias ----------------
__global__ __launch_bounds__(256) void redk_k(float* __restrict__ xbuf,
                                              const float* __restrict__ part,
                                              const float* __restrict__ bias) {
    const long total = (long)TOK * DIM;
    for (long idx = blockIdx.x * 256 + threadIdx.x; idx < total; idx += (long)gridDim.x * 256) {
        int col = (int)(idx % DIM);
        xbuf[idx] += part[idx] + part[idx + total] + bias[col];
    }
}

// ---------------- head GEMM: 128x128, 2-phase dbuf (tiny, M=32) ----------------
__global__ __launch_bounds__(256) void gemm_h(const bf16_t* __restrict__ A,
                                              const bf16_t* __restrict__ Bt,
                                              const float* __restrict__ bias,
                                              float* __restrict__ Cf,
                                              int M, int N, int K) {
    __shared__ bf16_t sA[2][128][32];
    __shared__ bf16_t sB[2][128][32];
    int tid = threadIdx.x;
    int bm = blockIdx.x * 128, bn = blockIdx.y * 128;
    int wave = tid >> 6, lane = tid & 63;
    int wm = (wave >> 1) * 64, wn = (wave & 1) * 64;
    int la = lane & 15, lb = lane >> 4;
    int rowA[2], rowB[2], colE[2];
#pragma unroll
    for (int q = 0; q < 2; q++) {
        int li = (wave * 2 + q) * 64 + lane;
        int row = li >> 2;
        colE[q] = (li & 3) * 8;
        int ar = bm + row; if (ar > M - 1) ar = M - 1;
        int br = bn + row; if (br > N - 1) br = N - 1;
        rowA[q] = ar; rowB[q] = br;
    }
    f32x4 acc[4][4];
#pragma unroll
    for (int m = 0; m < 4; m++)
#pragma unroll
        for (int n = 0; n < 4; n++) acc[m][n] = zero4();
    int nt = K >> 5;
#pragma unroll
    for (int q = 0; q < 2; q++) {
        gload16(A  + (long)rowA[q] * K + colE[q], &sA[0][0][0] + (wave * 2 + q) * 512);
        gload16(Bt + (long)rowB[q] * K + colE[q], &sB[0][0][0] + (wave * 2 + q) * 512);
    }
    __syncthreads();
    for (int t = 0; t < nt; t++) {
        int cur = t & 1;
        if (t + 1 < nt) {
            int k0 = (t + 1) << 5;
#pragma unroll
            for (int q = 0; q < 2; q++) {
                gload16(A  + (long)rowA[q] * K + k0 + colE[q], &sA[cur ^ 1][0][0] + (wave * 2 + q) * 512);
                gload16(Bt + (long)rowB[q] * K + k0 + colE[q], &sB[cur ^ 1][0][0] + (wave * 2 + q) * 512);
            }
        }
        bf16x8 af[4], bfr[4];
#pragma unroll
        for (int m = 0; m < 4; m++) af[m]  = *(const bf16x8*)&sA[cur][wm + m * 16 + la][lb * 8];
#pragma unroll
        for (int n = 0; n < 4; n++) bfr[n] = *(const bf16x8*)&sB[cur][wn + n * 16 + la][lb * 8];
#pragma unroll
        for (int m = 0; m < 4; m++)
#pragma unroll
            for (int n = 0; n < 4; n++)
                acc[m][n] = mfma16(af[m], bfr[n], acc[m][n]);
        __syncthreads();
    }
#pragma unroll
    for (int m = 0; m < 4; m++) {
#pragma unroll
        for (int n = 0; n < 4; n++) {
            int ib = bm + wm + m * 16 + lb * 4;
            int jb = bn + wn + n * 16 + la;
            if (jb >= N) continue;
            float bv = bias[jb];
#pragma unroll
            for (int r = 0; r < 4; r++) {
                int i = ib + r;
                if (i >= M) continue;
                Cf[(long)i * N + jb] = acc[m][n][r] + bv;
            }
        }
    }
}

// ---------------- QK^T * scale -> dots (fp32, padded NP) ----------------
__global__ __launch_bounds__(256) void qk_k(const bf16_t* __restrict__ qkv,
                                            float* __restrict__ dots) {
    int bh = blockIdx.z;
    int b = bh / HEADS, h = bh % HEADS;
    int i0 = blockIdx.x * 64, j0 = blockIdx.y * 64;
    __shared__ bf16_t sQ[64][32], sK[64][32];
    int tid = threadIdx.x, wave = tid >> 6, lane = tid & 63;
    int wm = (wave >> 1) * 32, wn = (wave & 1) * 32;
    int la = lane & 15, lb = lane >> 4;
    f32x4 acc[2][2];
#pragma unroll
    for (int m = 0; m < 2; m++)
#pragma unroll
        for (int n = 0; n < 2; n++) acc[m][n] = zero4();

    int row = tid >> 2, col = (tid & 3) * 8;
    int qi = i0 + row; if (qi > SEQ - 1) qi = SEQ - 1;
    int kj = j0 + row; if (kj > SEQ - 1) kj = SEQ - 1;
    const bf16_t* qsrc = qkv + (((b * SEQ + qi) * 3 + 0) * HEADS + h) * DH + col;
    const bf16_t* ksrc = qkv + (((b * SEQ + kj) * 3 + 1) * HEADS + h) * DH + col;

#pragma unroll
    for (int d0 = 0; d0 < 64; d0 += 32) {
        *(bf16x8*)&sQ[row][col] = *(const bf16x8*)(qsrc + d0);
        *(bf16x8*)&sK[row][col] = *(const bf16x8*)(ksrc + d0);
        __syncthreads();
        bf16x8 af[2], bfr[2];
#pragma unroll
        for (int m = 0; m < 2; m++) af[m]  = *(const bf16x8*)&sQ[wm + m * 16 + la][lb * 8];
#pragma unroll
        for (int n = 0; n < 2; n++) bfr[n] = *(const bf16x8*)&sK[wn + n * 16 + la][lb * 8];
#pragma unroll
        for (int m = 0; m < 2; m++)
#pragma unroll
            for (int n = 0; n < 2; n++)
                acc[m][n] = mfma16(af[m], bfr[n], acc[m][n]);
        __syncthreads();
    }
#pragma unroll
    for (int m = 0; m < 2; m++)
#pragma unroll
        for (int n = 0; n < 2; n++)
#pragma unroll
            for (int r = 0; r < 4; r++) {
                int i = i0 + wm + m * 16 + lb * 4 + r;
                int j = j0 + wn + n * 16 + la;
                if (i < SEQ && j < SEQ)
                    dots[((long)bh * SEQ + i) * NP + j] = acc[m][n][r] * 0.125f;
            }
}

// ======== fused softmax + re-attention + PV, one block per (b, 8-row i-tile) ========
// phase 1: row softmax (fp32) for 12 heads x 8 rows -> sm LDS (exact smre code)
// phase 2: head-mix + LN across heads per (r,j) -> bf16 P LDS (exact smre code)
// phase 3: per-wave PV (3 heads/wave) with pv_k's verified transposed-V staging.
// attn2 global buffer eliminated.
__global__ __launch_bounds__(256) void smrepv_k(const float* __restrict__ dots,
                                                const bf16_t* __restrict__ qkv,
                                                const float* __restrict__ W,
                                                const float* __restrict__ gg,
                                                const float* __restrict__ bb,
                                                bf16_t* __restrict__ aout) {
    __shared__ __align__(16) float  sm[HEADS][8][NP];    // 86 KB
    __shared__ __align__(16) bf16_t sP[HEADS][8][NP];    // 43 KB
    __shared__ __align__(16) bf16_t sVt[4][64][32];      // 16 KB (per-wave)
    __shared__ float sW[HEADS * HEADS];
    __shared__ float sg[HEADS], sb[HEADS];
    int tid = threadIdx.x;
    if (tid < HEADS * HEADS) sW[tid] = W[tid];
    if (tid < HEADS) { sg[tid] = gg[tid]; sb[tid] = bb[tid]; }
    int b = blockIdx.x / ITILES, it = blockIdx.x % ITILES;
    int i0 = it * 8;
    int wave = tid >> 6, lane = tid & 63;
    int nrow = SEQ - i0; if (nrow > 8) nrow = 8;

    // ---- phase 1: softmax ----
    for (int h = wave; h < HEADS; h += 4) {
        for (int r = 0; r < 8; r++) {
            if (r >= nrow) {
#pragma unroll
                for (int q = 0; q < 4; q++) { int j = lane + 64 * q; if (j < NP) sm[h][r][j] = 0.f; }
                continue;
            }
            const float* p = dots + ((long)(b * HEADS + h) * SEQ + i0 + r) * NP;
            float v[4], e[4];
#pragma unroll
            for (int q = 0; q < 4; q++) { int j = lane + 64 * q; v[q] = (j < SEQ) ? p[j] : -3.0e38f; }
            float mx = fmaxf(fmaxf(v[0], v[1]), fmaxf(v[2], v[3]));
#pragma unroll
            for (int o = 1; o < 64; o <<= 1) mx = fmaxf(mx, __shfl_xor(mx, o));
            float s = 0.f;
#pragma unroll
            for (int q = 0; q < 4; q++) {
                int j = lane + 64 * q;
                e[q] = (j < SEQ) ? __expf(v[q] - mx) : 0.f;
                s += e[q];
            }
#pragma unroll
            for (int o = 1; o < 64; o <<= 1) s += __shfl_xor(s, o);
            float inv = 1.f / s;
#pragma unroll
            for (int q = 0; q < 4; q++) { int j = lane + 64 * q; if (j < NP) sm[h][r][j] = e[q] * inv; }
        }
    }
    __syncthreads();

    // ---- phase 2: mix + LN over heads ----
    if (tid < NP) {
        int j = tid;
        bool valid = j < SEQ;
        for (int r = 0; r < 8; r++) {
            float vals[HEADS];
#pragma unroll
            for (int h = 0; h < HEADS; h++) vals[h] = valid ? sm[h][r][j] : 0.f;
            float mix[HEADS];
            float s = 0.f, sq = 0.f;
#pragma unroll
            for (int g = 0; g < HEADS; g++) {
                float a = 0.f;
#pragma unroll
                for (int h = 0; h < HEADS; h++) a += vals[h] * sW[h * HEADS + g];
                mix[g] = a; s += a; sq += a * a;
            }
            float m  = s * (1.f / 12.f);
            float rs = rsqrtf(sq * (1.f / 12.f) - m * m + 1e-5f);
#pragma unroll
            for (int g = 0; g < HEADS; g++)
                sP[g][r][j] = (bf16_t)(valid ? ((mix[g] - m) * rs * sg[g] + sb[g]) : 0.f);
        }
    }
    __syncthreads();

    // ---- phase 3: PV per wave (heads wave, wave+4, wave+8); no cross-wave sync ----
    int la = lane & 15, lb = lane >> 4;
    f32x4 acc[3][4];
#pragma unroll
    for (int hi = 0; hi < 3; hi++)
#pragma unroll
        for (int nf = 0; nf < 4; nf++) acc[hi][nf] = zero4();

    for (int hi = 0; hi < 3; hi++) {
        int g = wave + hi * 4;
        for (int j0 = 0; j0 < NP; j0 += 32) {
            // stage V tile [32 j][64 d] -> sVt[wave] transposed, pv_k's verified swizzle
#pragma unroll
            for (int c = 0; c < 4; c++) {
                int idx = c * 64 + lane;            // 0..255
                int jloc = idx >> 3;                // 0..31
                int dchunk = idx & 7;               // 0..7  (d0 = dchunk*8)
                int jg = j0 + jloc;
                bf16x8 vv;
#pragma unroll
                for (int e2 = 0; e2 < 8; e2++) vv[e2] = (bf16_t)0.f;
                if (jg < SEQ)
                    vv = *(const bf16x8*)(qkv + (((long)(b * SEQ + jg) * 3 + 2) * HEADS + g) * DH + dchunk * 8);
                int jlx = jloc ^ ((dchunk & 3) << 3);
#pragma unroll
                for (int e2 = 0; e2 < 8; e2++) sVt[wave][dchunk * 8 + e2][jlx] = vv[e2];
            }
            bf16x8 af;
            if (la < 8) af = *(const bf16x8*)&sP[g][la][j0 + lb * 8];
            else {
#pragma unroll
                for (int e2 = 0; e2 < 8; e2++) af[e2] = (bf16_t)0.f;
            }
#pragma unroll
            for (int nf = 0; nf < 4; nf++) {
                int rowd = nf * 16 + la;
                int colj = (lb * 8) ^ (((rowd >> 3) & 3) << 3);
                bf16x8 bfr = *(const bf16x8*)&sVt[wave][rowd][colj];
                acc[hi][nf] = mfma16(af, bfr, acc[hi][nf]);
            }
        }
    }
#pragma unroll
    for (int hi = 0; hi < 3; hi++) {
        int g = wave + hi * 4;
#pragma unroll
        for (int nf = 0; nf < 4; nf++) {
#pragma unroll
            for (int rr = 0; rr < 4; rr++) {
                int row = lb * 4 + rr;              // 0..15, valid rows < nrow
                if (row < nrow) {
                    int d = nf * 16 + la;
                    aout[((long)b * SEQ + i0 + row) * DIM + g * DH + d] = (bf16_t)acc[hi][nf][rr];
                }
            }
        }
    }
}

// ---------------- host orchestration ----------------
extern "C" void kernel_launch(void* const* d_in, const int* in_sizes, int n_in,
                              void* d_out, int out_size, void* d_ws, size_t ws_size,
                              hipStream_t stream) {
    const float* x        = (const float*)d_in[0];
    const float* cls      = (const float*)d_in[1];
    const float* ln1_g    = (const float*)d_in[2];
    const float* ln1_b    = (const float*)d_in[3];
    const float* w_qkv    = (const float*)d_in[4];
    const float* reattn_w = (const float*)d_in[5];
    const float* reattn_g = (const float*)d_in[6];
    const float* reattn_b = (const float*)d_in[7];
    const float* w_out    = (const float*)d_in[8];
    const float* b_out    = (const float*)d_in[9];
    const float* ln2_g    = (const float*)d_in[10];
    const float* ln2_b    = (const float*)d_in[11];
    const float* w1       = (const float*)d_in[12];
    const float* b1       = (const float*)d_in[13];
    const float* w2       = (const float*)d_in[14];
    const float* b2       = (const float*)d_in[15];
    const float* lnf_g    = (const float*)d_in[16];
    const float* lnf_b    = (const float*)d_in[17];
    const float* w_head   = (const float*)d_in[18];
    const float* b_head   = (const float*)d_in[19];
    float* out = (float*)d_out;

    char* p = (char*)d_ws;
    auto alloc = [&](size_t bytes) -> char* {
        char* r = p;
        p += (bytes + 255) & ~(size_t)255;
        return r;
    };
    bf16_t* wt      = (bf16_t*)alloc(2ULL * MLPD * DIM);
    bf16_t* wt_head = (bf16_t*)alloc(2ULL * FEAT * DIM);
    float*  xbuf    = (float*)alloc(4ULL * TOK * DIM);
    bf16_t* h_ln    = (bf16_t*)alloc(2ULL * TOK * DIM);
    bf16_t* qkv     = (bf16_t*)alloc(2ULL * TOK * 3 * DIM);
    float*  dots    = (float*)alloc(4ULL * BATCH * HEADS * SEQ * NP);
    bf16_t* h_mid   = (bf16_t*)dots;                               // lifetime-overlaid with dots
    float*  part    = (float*)alloc(8ULL * TOK * DIM);             // split-K partials (2 chunks fp32)
    bf16_t* aout    = (bf16_t*)alloc(2ULL * TOK * DIM);

    dim3 B256(256);
    concat_k<<<(TOK * DIM) / 256, B256, 0, stream>>>(x, cls, xbuf);
    tcvt_k<<<dim3((FEAT + 31) / 32, DIM / 32), B256, 0, stream>>>(w_head, wt_head, DIM, FEAT);

    for (int l = 0; l < DEPTH; l++) {
        ln_k<<<TOK, B256, 0, stream>>>(xbuf, DIM, ln1_g + l * DIM, ln1_b + l * DIM, h_ln);
        tcvt_k<<<dim3(2304 / 32, DIM / 32), B256, 0, stream>>>(w_qkv + (long)l * DIM * 2304, wt, DIM, 2304);
        gemm_k<0><<<dim3(50, 18), B256, 0, stream>>>(h_ln, wt, nullptr, nullptr, qkv, TOK, 2304, DIM, DIM);
        qk_k<<<dim3(4, 4, BATCH * HEADS), B256, 0, stream>>>(qkv, dots);
        smrepv_k<<<BATCH * ITILES, B256, 0, stream>>>(
            dots, qkv, reattn_w + l * HEADS * HEADS, reattn_g + l * HEADS, reattn_b + l * HEADS, aout);
        tcvt_k<<<dim3(DIM / 32, DIM / 32), B256, 0, stream>>>(w_out + (long)l * DIM * DIM, wt, DIM, DIM);
        gemm_k<1><<<dim3(50, 6), B256, 0, stream>>>(aout, wt, b_out + l * DIM, xbuf, nullptr, TOK, DIM, DIM, DIM);
        ln_k<<<TOK, B256, 0, stream>>>(xbuf, DIM, ln2_g + l * DIM, ln2_b + l * DIM, h_ln);
        tcvt_k<<<dim3(MLPD / 32, DIM / 32), B256, 0, stream>>>(w1 + (long)l * DIM * MLPD, wt, DIM, MLPD);
        gemm_k<2><<<dim3(50, 24), B256, 0, stream>>>(h_ln, wt, b1 + l * MLPD, nullptr, h_mid, TOK, MLPD, DIM, DIM);
        tcvt_k<<<dim3(DIM / 32, MLPD / 32), B256, 0, stream>>>(w2 + (long)l * MLPD * DIM, wt, MLPD, DIM);
        // MLP2: split-K x2 via blockIdx.z, partials then fused reduce (+bias, += residual)
        gemm_k<3><<<dim3(50, 6, 2), B256, 0, stream>>>(h_mid, wt, nullptr, part, nullptr,
                                                       TOK, DIM, MLPD, MLPD / 2);
        redk_k<<<2048, B256, 0, stream>>>(xbuf, part, b2 + l * DIM);
    }

    ln_k<<<BATCH, B256, 0, stream>>>(xbuf, (long)SEQ * DIM, lnf_g, lnf_b, h_ln);
    gemm_h<<<dim3(1, 8), B256, 0, stream>>>(h_ln, wt_head, b_head, out, BATCH, FEAT, DIM);
}

// Round 11
// 1891.685 us; speedup vs baseline: 1.4778x; 1.4778x over previous
//
#include <hip/hip_runtime.h>
#include <cstdint>

typedef __bf16 bf16_t;
typedef __bf16 bf16x8 __attribute__((ext_vector_type(8)));
typedef float  f32x4  __attribute__((ext_vector_type(4)));
typedef unsigned int u32;

#define DEPTH 6
#define HEADS 12
#define DH    64
#define DIM   768
#define MLPD  3072
#define FEAT  1000
#define BATCH 32
#define SEQ   197
#define NP    224          // padded j stride for attention matrices
#define TOK   (BATCH*SEQ)  // 6304

__device__ __forceinline__ f32x4 zero4() {
    f32x4 z; z[0] = 0.f; z[1] = 0.f; z[2] = 0.f; z[3] = 0.f; return z;
}

__device__ __forceinline__ f32x4 mfma16(bf16x8 a, bf16x8 b, f32x4 c) {
    return __builtin_amdgcn_mfma_f32_16x16x32_bf16(a, b, c, 0, 0, 0);
}

// async global->LDS, 16B per lane. lds base must be wave-uniform; HW adds lane*16.
typedef const __attribute__((address_space(1))) u32* gas_ptr;
typedef __attribute__((address_space(3))) u32*       las_ptr;
__device__ __forceinline__ void gload16(const bf16_t* g, bf16_t* l) {
    __builtin_amdgcn_global_load_lds((gas_ptr)g, (las_ptr)l, 16, 0, 0);
}

// ---------------- concat cls + x -> xbuf ----------------
__global__ __launch_bounds__(256) void concat_k(const float* __restrict__ x,
                                                const float* __restrict__ cls,
                                                float* __restrict__ xbuf) {
    int idx = blockIdx.x * 256 + threadIdx.x;      // exactly 6304*768 threads
    int col = idx % DIM;
    int row = idx / DIM;
    int b = row / SEQ, p = row % SEQ;
    xbuf[idx] = (p == 0) ? cls[col] : x[(b * 196 + p - 1) * DIM + col];
}

// ---------------- transpose + fp32->bf16:  W[K][N] -> Wt[N][K] ----------------
__global__ __launch_bounds__(256) void tcvt_k(const float* __restrict__ W,
                                              bf16_t* __restrict__ Wt,
                                              int K, int N) {
    __shared__ float t[32][33];
    int n0 = blockIdx.x * 32, k0 = blockIdx.y * 32;
    int c = threadIdx.x & 31, r = threadIdx.x >> 5;
#pragma unroll
    for (int i = 0; i < 4; i++) {
        int k = k0 + r + i * 8, n = n0 + c;        // K is always a multiple of 32
        t[r + i * 8][c] = (n < N) ? W[k * N + n] : 0.f;
    }
    __syncthreads();
#pragma unroll
    for (int i = 0; i < 4; i++) {
        int n = n0 + r + i * 8, k = k0 + c;
        if (n < N) Wt[n * K + k] = (bf16_t)t[c][r + i * 8];
    }
}

// ---------------- row LayerNorm over 768 cols, fp32 in -> bf16 out ----------------
__global__ __launch_bounds__(256) void ln_k(const float* __restrict__ x, long row_stride,
                                            const float* __restrict__ g,
                                            const float* __restrict__ b,
                                            bf16_t* __restrict__ out) {
    int row = blockIdx.x;
    const float* xr = x + (long)row * row_stride;
    int t = threadIdx.x;
    float v0 = xr[t], v1 = xr[t + 256], v2 = xr[t + 512];
    float s  = v0 + v1 + v2;
    float sq = v0 * v0 + v1 * v1 + v2 * v2;
#pragma unroll
    for (int o = 1; o < 64; o <<= 1) { s += __shfl_xor(s, o); sq += __shfl_xor(sq, o); }
    __shared__ float ss[4], sqs[4];
    int w = t >> 6;
    if ((t & 63) == 0) { ss[w] = s; sqs[w] = sq; }
    __syncthreads();
    s  = ss[0] + ss[1] + ss[2] + ss[3];
    sq = sqs[0] + sqs[1] + sqs[2] + sqs[3];
    float m  = s * (1.f / 768.f);
    float rs = rsqrtf(sq * (1.f / 768.f) - m * m + 1e-5f);
    bf16_t* orow = out + (long)row * DIM;
    orow[t]       = (bf16_t)((v0 - m) * rs * g[t]       + b[t]);
    orow[t + 256] = (bf16_t)((v1 - m) * rs * g[t + 256] + b[t + 256]);
    orow[t + 512] = (bf16_t)((v2 - m) * rs * g[t + 512] + b[t + 512]);
}

// ====== big GEMM: r3 schedule widened to 128x256, 512 thr / 8 waves (2m x 4n) ======
// Per-wave interval identical to r3 (16 MFMA, 8 ds_read_b128, <=3 gload issues); block
// count halves -> half the block-intervals per CU. 2-buf 48KB LDS, __syncthreads drain.
// MODE 0: Cb=acc; 1: Cf+=acc+bias; 2: Cb=gelu(acc+bias); 3: Cf[kc*M*N+..]=acc (split-K)
template <int MODE>
__global__ __launch_bounds__(512) void gemm_k(const bf16_t* __restrict__ A,
                                              const bf16_t* __restrict__ Bt,
                                              const float* __restrict__ bias,
                                              float* __restrict__ Cf,
                                              bf16_t* __restrict__ Cb,
                                              int M, int N, int Kstride, int Klen) {
    __shared__ bf16_t sA[2][128][32];   // 16 KB
    __shared__ bf16_t sB[2][256][32];   // 32 KB
    int tid = threadIdx.x;
    int bm = blockIdx.x * 128, bn = blockIdx.y * 256;
    long koff = (long)blockIdx.z * Klen;
    int wave = tid >> 6, lane = tid & 63;
    int wm = (wave >> 2) * 64, wn = (wave & 3) * 64;
    int la = lane & 15, lb = lane >> 4;

    // staging: A = 1 issue of 8KB (512 thr x 16B), B = 2 issues. thread: row tid>>2,
    // col (tid&3)*8. LDS dest linear, wave-uniform base (+ lane*16B in HW).
    int trow = tid >> 2, colE = (tid & 3) * 8;
    int rowA = bm + trow; if (rowA > M - 1) rowA = M - 1;
    int rowB0 = bn + trow, rowB1 = bn + 128 + trow;   // N multiple of 256

    f32x4 acc[4][4];
#pragma unroll
    for (int m = 0; m < 4; m++)
#pragma unroll
        for (int n = 0; n < 4; n++) acc[m][n] = zero4();

    auto stage = [&](int buf, long k0) {
        gload16(A  + (long)rowA  * Kstride + k0 + colE, &sA[buf][0][0] + wave * 512);
        gload16(Bt + (long)rowB0 * Kstride + k0 + colE, &sB[buf][0][0] + wave * 512);
        gload16(Bt + (long)rowB1 * Kstride + k0 + colE, &sB[buf][0][0] + 4096 + wave * 512);
    };

    int nt = Klen >> 5;
    stage(0, koff);
    __syncthreads();
    for (int t = 0; t < nt; t++) {
        int cur = t & 1;
        if (t + 1 < nt) stage(cur ^ 1, koff + ((long)(t + 1) << 5));
        bf16x8 af[4], bfr[4];
#pragma unroll
        for (int m = 0; m < 4; m++) af[m]  = *(const bf16x8*)&sA[cur][wm + m * 16 + la][lb * 8];
#pragma unroll
        for (int n = 0; n < 4; n++) bfr[n] = *(const bf16x8*)&sB[cur][wn + n * 16 + la][lb * 8];
#pragma unroll
        for (int m = 0; m < 4; m++)
#pragma unroll
            for (int n = 0; n < 4; n++)
                acc[m][n] = mfma16(af[m], bfr[n], acc[m][n]);
        __syncthreads();   // implicit vmcnt(0): publishes next buf + protects cur
    }

    long kout = (long)blockIdx.z * M * (long)N;   // split-K output chunk offset
#pragma unroll
    for (int m = 0; m < 4; m++) {
#pragma unroll
        for (int n = 0; n < 4; n++) {
            int ib = bm + wm + m * 16 + lb * 4;
            int jb = bn + wn + n * 16 + la;       // < N always (N mult of 256)
            float bv = (MODE == 1 || MODE == 2) ? bias[jb] : 0.f;
#pragma unroll
            for (int r = 0; r < 4; r++) {
                int i = ib + r;
                if (i >= M) continue;
                float v = acc[m][n][r];
                if (MODE == 0) {
                    Cb[(long)i * N + jb] = (bf16_t)v;
                } else if (MODE == 1) {
                    Cf[(long)i * N + jb] += v + bv;
                } else if (MODE == 2) {
                    float u = v + bv;
                    Cb[(long)i * N + jb] = (bf16_t)(0.5f * u * (1.f + erff(u * 0.70710678118f)));
                } else {
                    Cf[kout + (long)i * N + jb] = v;
                }
            }
        }
    }
}

// ---------------- split-K reduce: xbuf += p0 + p1 + bias ----------------
__global__ __launch_bounds__(256) void redk_k(float* __restrict__ xbuf,
                                              const float* __restrict__ part,
                                              const float* __restrict__ bias) {
    const long total = (long)TOK * DIM;
    for (long idx = blockIdx.x * 256 + threadIdx.x; idx < total; idx += (long)gridDim.x * 256) {
        int col = (int)(idx % DIM);
        xbuf[idx] += part[idx] + part[idx + total] + bias[col];
    }
}

// ---------------- head GEMM: 128x128, 2-phase dbuf (tiny, M=32) ----------------
__global__ __launch_bounds__(256) void gemm_h(const bf16_t* __restrict__ A,
                                              const bf16_t* __restrict__ Bt,
                                              const float* __restrict__ bias,
                                              float* __restrict__ Cf,
                                              int M, int N, int K) {
    __shared__ bf16_t sA[2][128][32];
    __shared__ bf16_t sB[2][128][32];
    int tid = threadIdx.x;
    int bm = blockIdx.x * 128, bn = blockIdx.y * 128;
    int wave = tid >> 6, lane = tid & 63;
    int wm = (wave >> 1) * 64, wn = (wave & 1) * 64;
    int la = lane & 15, lb = lane >> 4;
    int rowA[2], rowB[2], colE[2];
#pragma unroll
    for (int q = 0; q < 2; q++) {
        int li = (wave * 2 + q) * 64 + lane;
        int row = li >> 2;
        colE[q] = (li & 3) * 8;
        int ar = bm + row; if (ar > M - 1) ar = M - 1;
        int br = bn + row; if (br > N - 1) br = N - 1;
        rowA[q] = ar; rowB[q] = br;
    }
    f32x4 acc[4][4];
#pragma unroll
    for (int m = 0; m < 4; m++)
#pragma unroll
        for (int n = 0; n < 4; n++) acc[m][n] = zero4();
    int nt = K >> 5;
#pragma unroll
    for (int q = 0; q < 2; q++) {
        gload16(A  + (long)rowA[q] * K + colE[q], &sA[0][0][0] + (wave * 2 + q) * 512);
        gload16(Bt + (long)rowB[q] * K + colE[q], &sB[0][0][0] + (wave * 2 + q) * 512);
    }
    __syncthreads();
    for (int t = 0; t < nt; t++) {
        int cur = t & 1;
        if (t + 1 < nt) {
            int k0 = (t + 1) << 5;
#pragma unroll
            for (int q = 0; q < 2; q++) {
                gload16(A  + (long)rowA[q] * K + k0 + colE[q], &sA[cur ^ 1][0][0] + (wave * 2 + q) * 512);
                gload16(Bt + (long)rowB[q] * K + k0 + colE[q], &sB[cur ^ 1][0][0] + (wave * 2 + q) * 512);
            }
        }
        bf16x8 af[4], bfr[4];
#pragma unroll
        for (int m = 0; m < 4; m++) af[m]  = *(const bf16x8*)&sA[cur][wm + m * 16 + la][lb * 8];
#pragma unroll
        for (int n = 0; n < 4; n++) bfr[n] = *(const bf16x8*)&sB[cur][wn + n * 16 + la][lb * 8];
#pragma unroll
        for (int m = 0; m < 4; m++)
#pragma unroll
            for (int n = 0; n < 4; n++)
                acc[m][n] = mfma16(af[m], bfr[n], acc[m][n]);
        __syncthreads();
    }
#pragma unroll
    for (int m = 0; m < 4; m++) {
#pragma unroll
        for (int n = 0; n < 4; n++) {
            int ib = bm + wm + m * 16 + lb * 4;
            int jb = bn + wn + n * 16 + la;
            if (jb >= N) continue;
            float bv = bias[jb];
#pragma unroll
            for (int r = 0; r < 4; r++) {
                int i = ib + r;
                if (i >= M) continue;
                Cf[(long)i * N + jb] = acc[m][n][r] + bv;
            }
        }
    }
}

// ---------------- QK^T * scale -> dots (fp32, padded NP) ----------------
__global__ __launch_bounds__(256) void qk_k(const bf16_t* __restrict__ qkv,
                                            float* __restrict__ dots) {
    int bh = blockIdx.z;
    int b = bh / HEADS, h = bh % HEADS;
    int i0 = blockIdx.x * 64, j0 = blockIdx.y * 64;
    __shared__ bf16_t sQ[64][32], sK[64][32];
    int tid = threadIdx.x, wave = tid >> 6, lane = tid & 63;
    int wm = (wave >> 1) * 32, wn = (wave & 1) * 32;
    int la = lane & 15, lb = lane >> 4;
    f32x4 acc[2][2];
#pragma unroll
    for (int m = 0; m < 2; m++)
#pragma unroll
        for (int n = 0; n < 2; n++) acc[m][n] = zero4();

    int row = tid >> 2, col = (tid & 3) * 8;
    int qi = i0 + row; if (qi > SEQ - 1) qi = SEQ - 1;
    int kj = j0 + row; if (kj > SEQ - 1) kj = SEQ - 1;
    const bf16_t* qsrc = qkv + (((b * SEQ + qi) * 3 + 0) * HEADS + h) * DH + col;
    const bf16_t* ksrc = qkv + (((b * SEQ + kj) * 3 + 1) * HEADS + h) * DH + col;

#pragma unroll
    for (int d0 = 0; d0 < 64; d0 += 32) {
        *(bf16x8*)&sQ[row][col] = *(const bf16x8*)(qsrc + d0);
        *(bf16x8*)&sK[row][col] = *(const bf16x8*)(ksrc + d0);
        __syncthreads();
        bf16x8 af[2], bfr[2];
#pragma unroll
        for (int m = 0; m < 2; m++) af[m]  = *(const bf16x8*)&sQ[wm + m * 16 + la][lb * 8];
#pragma unroll
        for (int n = 0; n < 2; n++) bfr[n] = *(const bf16x8*)&sK[wn + n * 16 + la][lb * 8];
#pragma unroll
        for (int m = 0; m < 2; m++)
#pragma unroll
            for (int n = 0; n < 2; n++)
                acc[m][n] = mfma16(af[m], bfr[n], acc[m][n]);
        __syncthreads();
    }
#pragma unroll
    for (int m = 0; m < 2; m++)
#pragma unroll
        for (int n = 0; n < 2; n++)
#pragma unroll
            for (int r = 0; r < 4; r++) {
                int i = i0 + wm + m * 16 + lb * 4 + r;
                int j = j0 + wn + n * 16 + la;
                if (i < SEQ && j < SEQ)
                    dots[((long)bh * SEQ + i) * NP + j] = acc[m][n][r] * 0.125f;
            }
}

// ---------------- fused softmax + re-attention (head mix + LN) -> attn2 (bf16) ----------------
__global__ __launch_bounds__(256) void smre_k(const float* __restrict__ dots,
                                              const float* __restrict__ W,
                                              const float* __restrict__ gg,
                                              const float* __restrict__ bb,
                                              bf16_t* __restrict__ attn2) {
    __shared__ float sm[HEADS][NP];
    __shared__ float sW[HEADS * HEADS];
    __shared__ float sg[HEADS], sb[HEADS];
    int tid = threadIdx.x;
    if (tid < HEADS * HEADS) sW[tid] = W[tid];
    if (tid < HEADS) { sg[tid] = gg[tid]; sb[tid] = bb[tid]; }
    int bi = blockIdx.x;             // b*SEQ + i
    int b = bi / SEQ, i = bi % SEQ;
    int wave = tid >> 6, lane = tid & 63;

    for (int h = wave; h < HEADS; h += 4) {
        const float* p = dots + ((long)(b * HEADS + h) * SEQ + i) * NP;
        float v[4], e[4];
#pragma unroll
        for (int q = 0; q < 4; q++) { int j = lane + 64 * q; v[q] = (j < SEQ) ? p[j] : -3.0e38f; }
        float mx = fmaxf(fmaxf(v[0], v[1]), fmaxf(v[2], v[3]));
#pragma unroll
        for (int o = 1; o < 64; o <<= 1) mx = fmaxf(mx, __shfl_xor(mx, o));
        float s = 0.f;
#pragma unroll
        for (int q = 0; q < 4; q++) {
            int j = lane + 64 * q;
            e[q] = (j < SEQ) ? __expf(v[q] - mx) : 0.f;
            s += e[q];
        }
#pragma unroll
        for (int o = 1; o < 64; o <<= 1) s += __shfl_xor(s, o);
        float inv = 1.f / s;
#pragma unroll
        for (int q = 0; q < 4; q++) { int j = lane + 64 * q; if (j < NP) sm[h][j] = e[q] * inv; }
    }
    __syncthreads();

    int j = tid;
    if (j >= NP) return;
    bool valid = j < SEQ;
    float vals[HEADS];
#pragma unroll
    for (int h = 0; h < HEADS; h++) vals[h] = valid ? sm[h][j] : 0.f;
    float mix[HEADS];
    float s = 0.f, sq = 0.f;
#pragma unroll
    for (int g = 0; g < HEADS; g++) {
        float a = 0.f;
#pragma unroll
        for (int h = 0; h < HEADS; h++) a += vals[h] * sW[h * HEADS + g];
        mix[g] = a; s += a; sq += a * a;
    }
    float m  = s * (1.f / 12.f);
    float rs = rsqrtf(sq * (1.f / 12.f) - m * m + 1e-5f);
    long base = ((long)(b * HEADS) * SEQ + i) * NP + j;
    const long hs = (long)SEQ * NP;
#pragma unroll
    for (int g = 0; g < HEADS; g++) {
        float o = valid ? ((mix[g] - m) * rs * sg[g] + sb[g]) : 0.f;
        attn2[base + g * hs] = (bf16_t)o;
    }
}

// ---------------- PV: out[b,h,i,d] = sum_j attn2 * v  -> aout[b,i,h*64+d] (bf16) ----------------
__global__ __launch_bounds__(256) void pv_k(const bf16_t* __restrict__ attn2,
                                            const bf16_t* __restrict__ qkv,
                                            bf16_t* __restrict__ aout) {
    int bh = blockIdx.y;
    int b = bh / HEADS, h = bh % HEADS;
    int i0 = blockIdx.x * 64;
    __shared__ bf16_t sP[64][32];
    __shared__ bf16_t sVt[64][32];   // logical [d][j], XOR-swizzled on j-blocks
    int tid = threadIdx.x, wave = tid >> 6, lane = tid & 63;
    int wm = (wave >> 1) * 32, wn = (wave & 1) * 32;
    int la = lane & 15, lb = lane >> 4;
    f32x4 acc[2][2];
#pragma unroll
    for (int m = 0; m < 2; m++)
#pragma unroll
        for (int n = 0; n < 2; n++) acc[m][n] = zero4();

    int prow = tid >> 2, pcol = (tid & 3) * 8;
    int pi = i0 + prow; if (pi > SEQ - 1) pi = SEQ - 1;
    const bf16_t* psrc = attn2 + ((long)bh * SEQ + pi) * NP + pcol;
    int jl = tid >> 3, dblk = (tid & 7) * 8;
    int jlx = jl ^ ((tid & 3) << 3);

    for (int j0 = 0; j0 < NP; j0 += 32) {
        *(bf16x8*)&sP[prow][pcol] = *(const bf16x8*)(psrc + j0);
        int jg = j0 + jl;
        bf16x8 vv;
#pragma unroll
        for (int e = 0; e < 8; e++) vv[e] = (bf16_t)0.f;
        if (jg < SEQ)
            vv = *(const bf16x8*)(qkv + (((b * SEQ + jg) * 3 + 2) * HEADS + h) * DH + dblk);
#pragma unroll
        for (int e = 0; e < 8; e++) sVt[dblk + e][jlx] = vv[e];
        __syncthreads();
        bf16x8 af[2], bfr[2];
#pragma unroll
        for (int m = 0; m < 2; m++) af[m] = *(const bf16x8*)&sP[wm + m * 16 + la][lb * 8];
#pragma unroll
        for (int n = 0; n < 2; n++) {
            int rowd = wn + n * 16 + la;
            int colj = (lb * 8) ^ (((rowd >> 3) & 3) << 3);
            bfr[n] = *(const bf16x8*)&sVt[rowd][colj];
        }
#pragma unroll
        for (int m = 0; m < 2; m++)
#pragma unroll
            for (int n = 0; n < 2; n++)
                acc[m][n] = mfma16(af[m], bfr[n], acc[m][n]);
        __syncthreads();
    }
#pragma unroll
    for (int m = 0; m < 2; m++)
#pragma unroll
        for (int n = 0; n < 2; n++)
#pragma unroll
            for (int r = 0; r < 4; r++) {
                int i = i0 + wm + m * 16 + lb * 4 + r;
                int d = wn + n * 16 + la;
                if (i < SEQ)
                    aout[((long)b * SEQ + i) * DIM + h * DH + d] = (bf16_t)acc[m][n][r];
            }
}

// ---------------- host orchestration ----------------
extern "C" void kernel_launch(void* const* d_in, const int* in_sizes, int n_in,
                              void* d_out, int out_size, void* d_ws, size_t ws_size,
                              hipStream_t stream) {
    const float* x        = (const float*)d_in[0];
    const float* cls      = (const float*)d_in[1];
    const float* ln1_g    = (const float*)d_in[2];
    const float* ln1_b    = (const float*)d_in[3];
    const float* w_qkv    = (const float*)d_in[4];
    const float* reattn_w = (const float*)d_in[5];
    const float* reattn_g = (const float*)d_in[6];
    const float* reattn_b = (const float*)d_in[7];
    const float* w_out    = (const float*)d_in[8];
    const float* b_out    = (const float*)d_in[9];
    const float* ln2_g    = (const float*)d_in[10];
    const float* ln2_b    = (const float*)d_in[11];
    const float* w1       = (const float*)d_in[12];
    const float* b1       = (const float*)d_in[13];
    const float* w2       = (const float*)d_in[14];
    const float* b2       = (const float*)d_in[15];
    const float* lnf_g    = (const float*)d_in[16];
    const float* lnf_b    = (const float*)d_in[17];
    const float* w_head   = (const float*)d_in[18];
    const float* b_head   = (const float*)d_in[19];
    float* out = (float*)d_out;

    char* p = (char*)d_ws;
    auto alloc = [&](size_t bytes) -> char* {
        char* r = p;
        p += (bytes + 255) & ~(size_t)255;
        return r;
    };
    bf16_t* wt      = (bf16_t*)alloc(2ULL * MLPD * DIM);
    bf16_t* wt_head = (bf16_t*)alloc(2ULL * FEAT * DIM);
    float*  xbuf    = (float*)alloc(4ULL * TOK * DIM);
    bf16_t* h_ln    = (bf16_t*)alloc(2ULL * TOK * DIM);
    bf16_t* qkv     = (bf16_t*)alloc(2ULL * TOK * 3 * DIM);
    float*  dots    = (float*)alloc(4ULL * BATCH * HEADS * SEQ * NP);
    bf16_t* h_mid   = (bf16_t*)dots;                               // lifetime-overlaid with dots
    bf16_t* attn2   = (bf16_t*)alloc(2ULL * BATCH * HEADS * SEQ * NP);
    bf16_t* aout    = (bf16_t*)alloc(2ULL * TOK * DIM);
    // split-K partials (2 x TOK x DIM fp32 = 38.7MB) overlay attn2 (43.3MB): attn2 is
    // dead during MLP2 (consumed by pv_k) and fully rewritten next layer.
    float*  part    = (float*)attn2;

    dim3 B256(256), B512(512);
    concat_k<<<(TOK * DIM) / 256, B256, 0, stream>>>(x, cls, xbuf);
    tcvt_k<<<dim3((FEAT + 31) / 32, DIM / 32), B256, 0, stream>>>(w_head, wt_head, DIM, FEAT);

    for (int l = 0; l < DEPTH; l++) {
        ln_k<<<TOK, B256, 0, stream>>>(xbuf, DIM, ln1_g + l * DIM, ln1_b + l * DIM, h_ln);
        tcvt_k<<<dim3(2304 / 32, DIM / 32), B256, 0, stream>>>(w_qkv + (long)l * DIM * 2304, wt, DIM, 2304);
        gemm_k<0><<<dim3(50, 9), B512, 0, stream>>>(h_ln, wt, nullptr, nullptr, qkv, TOK, 2304, DIM, DIM);
        qk_k<<<dim3(4, 4, BATCH * HEADS), B256, 0, stream>>>(qkv, dots);
        smre_k<<<TOK, B256, 0, stream>>>(
            dots, reattn_w + l * HEADS * HEADS, reattn_g + l * HEADS, reattn_b + l * HEADS, attn2);
        pv_k<<<dim3(4, BATCH * HEADS), B256, 0, stream>>>(attn2, qkv, aout);
        tcvt_k<<<dim3(DIM / 32, DIM / 32), B256, 0, stream>>>(w_out + (long)l * DIM * DIM, wt, DIM, DIM);
        gemm_k<1><<<dim3(50, 3), B512, 0, stream>>>(aout, wt, b_out + l * DIM, xbuf, nullptr, TOK, DIM, DIM, DIM);
        ln_k<<<TOK, B256, 0, stream>>>(xbuf, DIM, ln2_g + l * DIM, ln2_b + l * DIM, h_ln);
        tcvt_k<<<dim3(MLPD / 32, DIM / 32), B256, 0, stream>>>(w1 + (long)l * DIM * MLPD, wt, DIM, MLPD);
        gemm_k<2><<<dim3(50, 12), B512, 0, stream>>>(h_ln, wt, b1 + l * MLPD, nullptr, h_mid, TOK, MLPD, DIM, DIM);
        tcvt_k<<<dim3(DIM / 32, MLPD / 32), B256, 0, stream>>>(w2 + (long)l * MLPD * DIM, wt, MLPD, DIM);
        // MLP2: split-K x2 via blockIdx.z, partials then fused reduce (+bias, += residual)
        gemm_k<3><<<dim3(50, 3, 2), B512, 0, stream>>>(h_mid, wt, nullptr, part, nullptr,
                                                       TOK, DIM, MLPD, MLPD / 2);
        redk_k<<<2048, B256, 0, stream>>>(xbuf, part, b2 + l * DIM);
    }

    ln_k<<<BATCH, B256, 0, stream>>>(xbuf, (long)SEQ * DIM, lnf_g, lnf_b, h_ln);
    gemm_h<<<dim3(1, 8), B256, 0, stream>>>(h_ln, wt_head, b_head, out, BATCH, FEAT, DIM);
}

// Round 13
// 1795.411 us; speedup vs baseline: 1.5571x; 1.0536x over previous
//
#include <hip/hip_runtime.h>
#include <cstdint>

typedef __bf16 bf16_t;
typedef __bf16 bf16x8 __attribute__((ext_vector_type(8)));
typedef float  f32x4  __attribute__((ext_vector_type(4)));
typedef unsigned int u32;

#define DEPTH 6
#define HEADS 12
#define DH    64
#define DIM   768
#define MLPD  3072
#define FEAT  1000
#define BATCH 32
#define SEQ   197
#define NP    224          // padded j stride for attention matrices
#define TOK   (BATCH*SEQ)  // 6304

__device__ __forceinline__ f32x4 zero4() {
    f32x4 z; z[0] = 0.f; z[1] = 0.f; z[2] = 0.f; z[3] = 0.f; return z;
}

__device__ __forceinline__ f32x4 mfma16(bf16x8 a, bf16x8 b, f32x4 c) {
    return __builtin_amdgcn_mfma_f32_16x16x32_bf16(a, b, c, 0, 0, 0);
}

// async global->LDS, 16B per lane. lds base must be wave-uniform; HW adds lane*16.
typedef const __attribute__((address_space(1))) u32* gas_ptr;
typedef __attribute__((address_space(3))) u32*       las_ptr;
__device__ __forceinline__ void gload16(const bf16_t* g, bf16_t* l) {
    __builtin_amdgcn_global_load_lds((gas_ptr)g, (las_ptr)l, 16, 0, 0);
}

// ---------------- concat cls + x -> xbuf ----------------
__global__ __launch_bounds__(256) void concat_k(const float* __restrict__ x,
                                                const float* __restrict__ cls,
                                                float* __restrict__ xbuf) {
    int idx = blockIdx.x * 256 + threadIdx.x;      // exactly 6304*768 threads
    int col = idx % DIM;
    int row = idx / DIM;
    int b = row / SEQ, p = row % SEQ;
    xbuf[idx] = (p == 0) ? cls[col] : x[(b * 196 + p - 1) * DIM + col];
}

// ---------------- transpose + fp32->bf16:  W[K][N] -> Wt[N][K] (head only) ----------------
__global__ __launch_bounds__(256) void tcvt_k(const float* __restrict__ W,
                                              bf16_t* __restrict__ Wt,
                                              int K, int N) {
    __shared__ float t[32][33];
    int n0 = blockIdx.x * 32, k0 = blockIdx.y * 32;
    int c = threadIdx.x & 31, r = threadIdx.x >> 5;
#pragma unroll
    for (int i = 0; i < 4; i++) {
        int k = k0 + r + i * 8, n = n0 + c;        // K is always a multiple of 32
        t[r + i * 8][c] = (n < N) ? W[k * N + n] : 0.f;
    }
    __syncthreads();
#pragma unroll
    for (int i = 0; i < 4; i++) {
        int n = n0 + r + i * 8, k = k0 + c;
        if (n < N) Wt[n * K + k] = (bf16_t)t[c][r + i * 8];
    }
}

// ------- batched transpose+convert of one layer's 4 weights in a single dispatch -------
// regions (all dims multiples of 32, no bounds checks):
//   qkv: K=768,N=2304  tiles 72x24=1728  dst off 0
//   out: K=768,N=768   tiles 24x24=576   dst off 1769472
//   w1 : K=768,N=3072  tiles 96x24=2304  dst off 2359296
//   w2 : K=3072,N=768  tiles 24x96=2304  dst off 4718592        (total 6912 tiles)
__global__ __launch_bounds__(256) void tcvtall_k(const float* __restrict__ wq,
                                                 const float* __restrict__ wo,
                                                 const float* __restrict__ w1p,
                                                 const float* __restrict__ w2p,
                                                 bf16_t* __restrict__ wt) {
    int id = blockIdx.x;
    const float* W; int K, N, ntx, rid; long doff;
    if (id < 1728)      { W = wq;  K = 768;  N = 2304; doff = 0;       ntx = 72; rid = id; }
    else if (id < 2304) { W = wo;  K = 768;  N = 768;  doff = 1769472; ntx = 24; rid = id - 1728; }
    else if (id < 4608) { W = w1p; K = 768;  N = 3072; doff = 2359296; ntx = 96; rid = id - 2304; }
    else                { W = w2p; K = 3072; N = 768;  doff = 4718592; ntx = 24; rid = id - 4608; }
    int n0 = (rid % ntx) * 32, k0 = (rid / ntx) * 32;
    __shared__ float t[32][33];
    int c = threadIdx.x & 31, r = threadIdx.x >> 5;
#pragma unroll
    for (int i = 0; i < 4; i++)
        t[r + i * 8][c] = W[(long)(k0 + r + i * 8) * N + n0 + c];
    __syncthreads();
#pragma unroll
    for (int i = 0; i < 4; i++)
        wt[doff + (long)(n0 + r + i * 8) * K + k0 + c] = (bf16_t)t[c][r + i * 8];
}

// ---------------- row LayerNorm over 768 cols, fp32 in -> bf16 out ----------------
__global__ __launch_bounds__(256) void ln_k(const float* __restrict__ x, long row_stride,
                                            const float* __restrict__ g,
                                            const float* __restrict__ b,
                                            bf16_t* __restrict__ out) {
    int row = blockIdx.x;
    const float* xr = x + (long)row * row_stride;
    int t = threadIdx.x;
    float v0 = xr[t], v1 = xr[t + 256], v2 = xr[t + 512];
    float s  = v0 + v1 + v2;
    float sq = v0 * v0 + v1 * v1 + v2 * v2;
#pragma unroll
    for (int o = 1; o < 64; o <<= 1) { s += __shfl_xor(s, o); sq += __shfl_xor(sq, o); }
    __shared__ float ss[4], sqs[4];
    int w = t >> 6;
    if ((t & 63) == 0) { ss[w] = s; sqs[w] = sq; }
    __syncthreads();
    s  = ss[0] + ss[1] + ss[2] + ss[3];
    sq = sqs[0] + sqs[1] + sqs[2] + sqs[3];
    float m  = s * (1.f / 768.f);
    float rs = rsqrtf(sq * (1.f / 768.f) - m * m + 1e-5f);
    bf16_t* orow = out + (long)row * DIM;
    orow[t]       = (bf16_t)((v0 - m) * rs * g[t]       + b[t]);
    orow[t + 256] = (bf16_t)((v1 - m) * rs * g[t + 256] + b[t + 256]);
    orow[t + 512] = (bf16_t)((v2 - m) * rs * g[t + 512] + b[t + 512]);
}

// ====== big GEMM: r3 schedule widened to 128x256, 512 thr / 8 waves (2m x 4n) ======
// MODE 0: Cb=acc; 1: Cf+=acc+bias; 2: Cb=gelu(acc+bias); 3: Cf[kc*M*N+..]=acc (split-K)
template <int MODE>
__global__ __launch_bounds__(512) void gemm_k(const bf16_t* __restrict__ A,
                                              const bf16_t* __restrict__ Bt,
                                              const float* __restrict__ bias,
                                              float* __restrict__ Cf,
                                              bf16_t* __restrict__ Cb,
                                              int M, int N, int Kstride, int Klen) {
    __shared__ bf16_t sA[2][128][32];   // 16 KB
    __shared__ bf16_t sB[2][256][32];   // 32 KB
    int tid = threadIdx.x;
    int bm = blockIdx.x * 128, bn = blockIdx.y * 256;
    long koff = (long)blockIdx.z * Klen;
    int wave = tid >> 6, lane = tid & 63;
    int wm = (wave >> 2) * 64, wn = (wave & 3) * 64;
    int la = lane & 15, lb = lane >> 4;

    int trow = tid >> 2, colE = (tid & 3) * 8;
    int rowA = bm + trow; if (rowA > M - 1) rowA = M - 1;
    int rowB0 = bn + trow, rowB1 = bn + 128 + trow;   // N multiple of 256

    f32x4 acc[4][4];
#pragma unroll
    for (int m = 0; m < 4; m++)
#pragma unroll
        for (int n = 0; n < 4; n++) acc[m][n] = zero4();

    auto stage = [&](int buf, long k0) {
        gload16(A  + (long)rowA  * Kstride + k0 + colE, &sA[buf][0][0] + wave * 512);
        gload16(Bt + (long)rowB0 * Kstride + k0 + colE, &sB[buf][0][0] + wave * 512);
        gload16(Bt + (long)rowB1 * Kstride + k0 + colE, &sB[buf][0][0] + 4096 + wave * 512);
    };

    int nt = Klen >> 5;
    stage(0, koff);
    __syncthreads();
    for (int t = 0; t < nt; t++) {
        int cur = t & 1;
        if (t + 1 < nt) stage(cur ^ 1, koff + ((long)(t + 1) << 5));
        bf16x8 af[4], bfr[4];
#pragma unroll
        for (int m = 0; m < 4; m++) af[m]  = *(const bf16x8*)&sA[cur][wm + m * 16 + la][lb * 8];
#pragma unroll
        for (int n = 0; n < 4; n++) bfr[n] = *(const bf16x8*)&sB[cur][wn + n * 16 + la][lb * 8];
#pragma unroll
        for (int m = 0; m < 4; m++)
#pragma unroll
            for (int n = 0; n < 4; n++)
                acc[m][n] = mfma16(af[m], bfr[n], acc[m][n]);
        __syncthreads();   // implicit vmcnt(0): publishes next buf + protects cur
    }

    long kout = (long)blockIdx.z * M * (long)N;   // split-K output chunk offset
#pragma unroll
    for (int m = 0; m < 4; m++) {
#pragma unroll
        for (int n = 0; n < 4; n++) {
            int ib = bm + wm + m * 16 + lb * 4;
            int jb = bn + wn + n * 16 + la;       // < N always (N mult of 256)
            float bv = (MODE == 1 || MODE == 2) ? bias[jb] : 0.f;
#pragma unroll
            for (int r = 0; r < 4; r++) {
                int i = ib + r;
                if (i >= M) continue;
                float v = acc[m][n][r];
                if (MODE == 0) {
                    Cb[(long)i * N + jb] = (bf16_t)v;
                } else if (MODE == 1) {
                    Cf[(long)i * N + jb] += v + bv;
                } else if (MODE == 2) {
                    float u = v + bv;
                    Cb[(long)i * N + jb] = (bf16_t)(0.5f * u * (1.f + erff(u * 0.70710678118f)));
                } else {
                    Cf[kout + (long)i * N + jb] = v;
                }
            }
        }
    }
}

// ---------------- split-K reduce: xbuf += p0 + p1 + bias ----------------
__global__ __launch_bounds__(256) void redk_k(float* __restrict__ xbuf,
                                              const float* __restrict__ part,
                                              const float* __restrict__ bias) {
    const long total = (long)TOK * DIM;
    for (long idx = blockIdx.x * 256 + threadIdx.x; idx < total; idx += (long)gridDim.x * 256) {
        int col = (int)(idx % DIM);
        xbuf[idx] += part[idx] + part[idx + total] + bias[col];
    }
}

// ---------------- head GEMM: 128x128, 2-phase dbuf (tiny, M=32) ----------------
__global__ __launch_bounds__(256) void gemm_h(const bf16_t* __restrict__ A,
                                              const bf16_t* __restrict__ Bt,
                                              const float* __restrict__ bias,
                                              float* __restrict__ Cf,
                                              int M, int N, int K) {
    __shared__ bf16_t sA[2][128][32];
    __shared__ bf16_t sB[2][128][32];
    int tid = threadIdx.x;
    int bm = blockIdx.x * 128, bn = blockIdx.y * 128;
    int wave = tid >> 6, lane = tid & 63;
    int wm = (wave >> 1) * 64, wn = (wave & 1) * 64;
    int la = lane & 15, lb = lane >> 4;
    int rowA[2], rowB[2], colE[2];
#pragma unroll
    for (int q = 0; q < 2; q++) {
        int li = (wave * 2 + q) * 64 + lane;
        int row = li >> 2;
        colE[q] = (li & 3) * 8;
        int ar = bm + row; if (ar > M - 1) ar = M - 1;
        int br = bn + row; if (br > N - 1) br = N - 1;
        rowA[q] = ar; rowB[q] = br;
    }
    f32x4 acc[4][4];
#pragma unroll
    for (int m = 0; m < 4; m++)
#pragma unroll
        for (int n = 0; n < 4; n++) acc[m][n] = zero4();
    int nt = K >> 5;
#pragma unroll
    for (int q = 0; q < 2; q++) {
        gload16(A  + (long)rowA[q] * K + colE[q], &sA[0][0][0] + (wave * 2 + q) * 512);
        gload16(Bt + (long)rowB[q] * K + colE[q], &sB[0][0][0] + (wave * 2 + q) * 512);
    }
    __syncthreads();
    for (int t = 0; t < nt; t++) {
        int cur = t & 1;
        if (t + 1 < nt) {
            int k0 = (t + 1) << 5;
#pragma unroll
            for (int q = 0; q < 2; q++) {
                gload16(A  + (long)rowA[q] * K + k0 + colE[q], &sA[cur ^ 1][0][0] + (wave * 2 + q) * 512);
                gload16(Bt + (long)rowB[q] * K + k0 + colE[q], &sB[cur ^ 1][0][0] + (wave * 2 + q) * 512);
            }
        }
        bf16x8 af[4], bfr[4];
#pragma unroll
        for (int m = 0; m < 4; m++) af[m]  = *(const bf16x8*)&sA[cur][wm + m * 16 + la][lb * 8];
#pragma unroll
        for (int n = 0; n < 4; n++) bfr[n] = *(const bf16x8*)&sB[cur][wn + n * 16 + la][lb * 8];
#pragma unroll
        for (int m = 0; m < 4; m++)
#pragma unroll
            for (int n = 0; n < 4; n++)
                acc[m][n] = mfma16(af[m], bfr[n], acc[m][n]);
        __syncthreads();
    }
#pragma unroll
    for (int m = 0; m < 4; m++) {
#pragma unroll
        for (int n = 0; n < 4; n++) {
            int ib = bm + wm + m * 16 + lb * 4;
            int jb = bn + wn + n * 16 + la;
            if (jb >= N) continue;
            float bv = bias[jb];
#pragma unroll
            for (int r = 0; r < 4; r++) {
                int i = ib + r;
                if (i >= M) continue;
                Cf[(long)i * N + jb] = acc[m][n][r] + bv;
            }
        }
    }
}

// ---------------- QK^T * scale -> dots (fp32, padded NP) ----------------
__global__ __launch_bounds__(256) void qk_k(const bf16_t* __restrict__ qkv,
                                            float* __restrict__ dots) {
    int bh = blockIdx.z;
    int b = bh / HEADS, h = bh % HEADS;
    int i0 = blockIdx.x * 64, j0 = blockIdx.y * 64;
    __shared__ bf16_t sQ[64][32], sK[64][32];
    int tid = threadIdx.x, wave = tid >> 6, lane = tid & 63;
    int wm = (wave >> 1) * 32, wn = (wave & 1) * 32;
    int la = lane & 15, lb = lane >> 4;
    f32x4 acc[2][2];
#pragma unroll
    for (int m = 0; m < 2; m++)
#pragma unroll
        for (int n = 0; n < 2; n++) acc[m][n] = zero4();

    int row = tid >> 2, col = (tid & 3) * 8;
    int qi = i0 + row; if (qi > SEQ - 1) qi = SEQ - 1;
    int kj = j0 + row; if (kj > SEQ - 1) kj = SEQ - 1;
    const bf16_t* qsrc = qkv + (((b * SEQ + qi) * 3 + 0) * HEADS + h) * DH + col;
    const bf16_t* ksrc = qkv + (((b * SEQ + kj) * 3 + 1) * HEADS + h) * DH + col;

#pragma unroll
    for (int d0 = 0; d0 < 64; d0 += 32) {
        *(bf16x8*)&sQ[row][col] = *(const bf16x8*)(qsrc + d0);
        *(bf16x8*)&sK[row][col] = *(const bf16x8*)(ksrc + d0);
        __syncthreads();
        bf16x8 af[2], bfr[2];
#pragma unroll
        for (int m = 0; m < 2; m++) af[m]  = *(const bf16x8*)&sQ[wm + m * 16 + la][lb * 8];
#pragma unroll
        for (int n = 0; n < 2; n++) bfr[n] = *(const bf16x8*)&sK[wn + n * 16 + la][lb * 8];
#pragma unroll
        for (int m = 0; m < 2; m++)
#pragma unroll
            for (int n = 0; n < 2; n++)
                acc[m][n] = mfma16(af[m], bfr[n], acc[m][n]);
        __syncthreads();
    }
#pragma unroll
    for (int m = 0; m < 2; m++)
#pragma unroll
        for (int n = 0; n < 2; n++)
#pragma unroll
            for (int r = 0; r < 4; r++) {
                int i = i0 + wm + m * 16 + lb * 4 + r;
                int j = j0 + wn + n * 16 + la;
                if (i < SEQ && j < SEQ)
                    dots[((long)bh * SEQ + i) * NP + j] = acc[m][n][r] * 0.125f;
            }
}

// ---------------- fused softmax + re-attention (head mix + LN) -> attn2 (bf16) ----------------
__global__ __launch_bounds__(256) void smre_k(const float* __restrict__ dots,
                                              const float* __restrict__ W,
                                              const float* __restrict__ gg,
                                              const float* __restrict__ bb,
                                              bf16_t* __restrict__ attn2) {
    __shared__ float sm[HEADS][NP];
    __shared__ float sW[HEADS * HEADS];
    __shared__ float sg[HEADS], sb[HEADS];
    int tid = threadIdx.x;
    if (tid < HEADS * HEADS) sW[tid] = W[tid];
    if (tid < HEADS) { sg[tid] = gg[tid]; sb[tid] = bb[tid]; }
    int bi = blockIdx.x;             // b*SEQ + i
    int b = bi / SEQ, i = bi % SEQ;
    int wave = tid >> 6, lane = tid & 63;

    for (int h = wave; h < HEADS; h += 4) {
        const float* p = dots + ((long)(b * HEADS + h) * SEQ + i) * NP;
        float v[4], e[4];
#pragma unroll
        for (int q = 0; q < 4; q++) { int j = lane + 64 * q; v[q] = (j < SEQ) ? p[j] : -3.0e38f; }
        float mx = fmaxf(fmaxf(v[0], v[1]), fmaxf(v[2], v[3]));
#pragma unroll
        for (int o = 1; o < 64; o <<= 1) mx = fmaxf(mx, __shfl_xor(mx, o));
        float s = 0.f;
#pragma unroll
        for (int q = 0; q < 4; q++) {
            int j = lane + 64 * q;
            e[q] = (j < SEQ) ? __expf(v[q] - mx) : 0.f;
            s += e[q];
        }
#pragma unroll
        for (int o = 1; o < 64; o <<= 1) s += __shfl_xor(s, o);
        float inv = 1.f / s;
#pragma unroll
        for (int q = 0; q < 4; q++) { int j = lane + 64 * q; if (j < NP) sm[h][j] = e[q] * inv; }
    }
    __syncthreads();

    int j = tid;
    if (j >= NP) return;
    bool valid = j < SEQ;
    float vals[HEADS];
#pragma unroll
    for (int h = 0; h < HEADS; h++) vals[h] = valid ? sm[h][j] : 0.f;
    float mix[HEADS];
    float s = 0.f, sq = 0.f;
#pragma unroll
    for (int g = 0; g < HEADS; g++) {
        float a = 0.f;
#pragma unroll
        for (int h = 0; h < HEADS; h++) a += vals[h] * sW[h * HEADS + g];
        mix[g] = a; s += a; sq += a * a;
    }
    float m  = s * (1.f / 12.f);
    float rs = rsqrtf(sq * (1.f / 12.f) - m * m + 1e-5f);
    long base = ((long)(b * HEADS) * SEQ + i) * NP + j;
    const long hs = (long)SEQ * NP;
#pragma unroll
    for (int g = 0; g < HEADS; g++) {
        float o = valid ? ((mix[g] - m) * rs * sg[g] + sb[g]) : 0.f;
        attn2[base + g * hs] = (bf16_t)o;
    }
}

// ---------------- PV: out[b,h,i,d] = sum_j attn2 * v  -> aout[b,i,h*64+d] (bf16) ----------------
__global__ __launch_bounds__(256) void pv_k(const bf16_t* __restrict__ attn2,
                                            const bf16_t* __restrict__ qkv,
                                            bf16_t* __restrict__ aout) {
    int bh = blockIdx.y;
    int b = bh / HEADS, h = bh % HEADS;
    int i0 = blockIdx.x * 64;
    __shared__ bf16_t sP[64][32];
    __shared__ bf16_t sVt[64][32];   // logical [d][j], XOR-swizzled on j-blocks
    int tid = threadIdx.x, wave = tid >> 6, lane = tid & 63;
    int wm = (wave >> 1) * 32, wn = (wave & 1) * 32;
    int la = lane & 15, lb = lane >> 4;
    f32x4 acc[2][2];
#pragma unroll
    for (int m = 0; m < 2; m++)
#pragma unroll
        for (int n = 0; n < 2; n++) acc[m][n] = zero4();

    int prow = tid >> 2, pcol = (tid & 3) * 8;
    int pi = i0 + prow; if (pi > SEQ - 1) pi = SEQ - 1;
    const bf16_t* psrc = attn2 + ((long)bh * SEQ + pi) * NP + pcol;
    int jl = tid >> 3, dblk = (tid & 7) * 8;
    int jlx = jl ^ ((tid & 3) << 3);

    for (int j0 = 0; j0 < NP; j0 += 32) {
        *(bf16x8*)&sP[prow][pcol] = *(const bf16x8*)(psrc + j0);
        int jg = j0 + jl;
        bf16x8 vv;
#pragma unroll
        for (int e = 0; e < 8; e++) vv[e] = (bf16_t)0.f;
        if (jg < SEQ)
            vv = *(const bf16x8*)(qkv + (((b * SEQ + jg) * 3 + 2) * HEADS + h) * DH + dblk);
#pragma unroll
        for (int e = 0; e < 8; e++) sVt[dblk + e][jlx] = vv[e];
        __syncthreads();
        bf16x8 af[2], bfr[2];
#pragma unroll
        for (int m = 0; m < 2; m++) af[m] = *(const bf16x8*)&sP[wm + m * 16 + la][lb * 8];
#pragma unroll
        for (int n = 0; n < 2; n++) {
            int rowd = wn + n * 16 + la;
            int colj = (lb * 8) ^ (((rowd >> 3) & 3) << 3);
            bfr[n] = *(const bf16x8*)&sVt[rowd][colj];
        }
#pragma unroll
        for (int m = 0; m < 2; m++)
#pragma unroll
            for (int n = 0; n < 2; n++)
                acc[m][n] = mfma16(af[m], bfr[n], acc[m][n]);
        __syncthreads();
    }
#pragma unroll
    for (int m = 0; m < 2; m++)
#pragma unroll
        for (int n = 0; n < 2; n++)
#pragma unroll
            for (int r = 0; r < 4; r++) {
                int i = i0 + wm + m * 16 + lb * 4 + r;
                int d = wn + n * 16 + la;
                if (i < SEQ)
                    aout[((long)b * SEQ + i) * DIM + h * DH + d] = (bf16_t)acc[m][n][r];
            }
}

// ---------------- host orchestration ----------------
extern "C" void kernel_launch(void* const* d_in, const int* in_sizes, int n_in,
                              void* d_out, int out_size, void* d_ws, size_t ws_size,
                              hipStream_t stream) {
    const float* x        = (const float*)d_in[0];
    const float* cls      = (const float*)d_in[1];
    const float* ln1_g    = (const float*)d_in[2];
    const float* ln1_b    = (const float*)d_in[3];
    const float* w_qkv    = (const float*)d_in[4];
    const float* reattn_w = (const float*)d_in[5];
    const float* reattn_g = (const float*)d_in[6];
    const float* reattn_b = (const float*)d_in[7];
    const float* w_out    = (const float*)d_in[8];
    const float* b_out    = (const float*)d_in[9];
    const float* ln2_g    = (const float*)d_in[10];
    const float* ln2_b    = (const float*)d_in[11];
    const float* w1       = (const float*)d_in[12];
    const float* b1       = (const float*)d_in[13];
    const float* w2       = (const float*)d_in[14];
    const float* b2       = (const float*)d_in[15];
    const float* lnf_g    = (const float*)d_in[16];
    const float* lnf_b    = (const float*)d_in[17];
    const float* w_head   = (const float*)d_in[18];
    const float* b_head   = (const float*)d_in[19];
    float* out = (float*)d_out;

    char* p = (char*)d_ws;
    auto alloc = [&](size_t bytes) -> char* {
        char* r = p;
        p += (bytes + 255) & ~(size_t)255;
        return r;
    };
    bf16_t* wt      = (bf16_t*)alloc(2ULL * 7077888);              // all 4 layer weights, transposed
    bf16_t* wt_head = (bf16_t*)alloc(2ULL * FEAT * DIM);
    float*  xbuf    = (float*)alloc(4ULL * TOK * DIM);
    bf16_t* h_ln    = (bf16_t*)alloc(2ULL * TOK * DIM);
    bf16_t* qkv     = (bf16_t*)alloc(2ULL * TOK * 3 * DIM);
    float*  dots    = (float*)alloc(4ULL * BATCH * HEADS * SEQ * NP);   // 67.8 MB
    bf16_t* h_mid   = (bf16_t*)dots;                               // MLP1 out overlays dots (38.7MB)
    bf16_t* attn2   = (bf16_t*)alloc(2ULL * BATCH * HEADS * SEQ * NP); // 33.9 MB
    bf16_t* aout    = (bf16_t*)alloc(2ULL * TOK * DIM);                // 9.7 MB
    // Split-K partial overlays (38.7 MB each), per-use-site safety:
    //  - OP partials overlay DOTS: dots dead after smre_k; h_mid (same region) written
    //    only at MLP1, after redk consumed the partials. aout (OP's input) untouched.
    //  - MLP2 partials overlay ATTN2(+aout tail): attn2 dead after pv_k; aout dead after
    //    OP gemm; both fully rewritten next layer. (attn2 is only 33.9MB; tail spills
    //    4.8MB into aout -- safe at this point, r11-proven.)
    float*  part_op = (float*)dots;
    float*  part_m2 = (float*)attn2;

    dim3 B256(256), B512(512);
    concat_k<<<(TOK * DIM) / 256, B256, 0, stream>>>(x, cls, xbuf);
    tcvt_k<<<dim3((FEAT + 31) / 32, DIM / 32), B256, 0, stream>>>(w_head, wt_head, DIM, FEAT);

    // transposed-weight region offsets within wt (elements)
    bf16_t* wqkv_t = wt;                 // [2304][768]
    bf16_t* wout_t = wt + 1769472;       // [768][768]
    bf16_t* w1_t   = wt + 2359296;       // [3072][768]
    bf16_t* w2_t   = wt + 4718592;       // [768][3072]

    for (int l = 0; l < DEPTH; l++) {
        tcvtall_k<<<6912, B256, 0, stream>>>(w_qkv + (long)l * DIM * 2304,
                                             w_out + (long)l * DIM * DIM,
                                             w1 + (long)l * DIM * MLPD,
                                             w2 + (long)l * MLPD * DIM, wt);
        ln_k<<<TOK, B256, 0, stream>>>(xbuf, DIM, ln1_g + l * DIM, ln1_b + l * DIM, h_ln);
        gemm_k<0><<<dim3(50, 9), B512, 0, stream>>>(h_ln, wqkv_t, nullptr, nullptr, qkv, TOK, 2304, DIM, DIM);
        qk_k<<<dim3(4, 4, BATCH * HEADS), B256, 0, stream>>>(qkv, dots);
        smre_k<<<TOK, B256, 0, stream>>>(
            dots, reattn_w + l * HEADS * HEADS, reattn_g + l * HEADS, reattn_b + l * HEADS, attn2);
        pv_k<<<dim3(4, BATCH * HEADS), B256, 0, stream>>>(attn2, qkv, aout);
        // OP: split-K x2, partials in dots region (dead), reduce folds b_out + residual
        gemm_k<3><<<dim3(50, 3, 2), B512, 0, stream>>>(aout, wout_t, nullptr, part_op, nullptr,
                                                       TOK, DIM, DIM, DIM / 2);
        redk_k<<<2048, B256, 0, stream>>>(xbuf, part_op, b_out + l * DIM);
        ln_k<<<TOK, B256, 0, stream>>>(xbuf, DIM, ln2_g + l * DIM, ln2_b + l * DIM, h_ln);
        gemm_k<2><<<dim3(50, 12), B512, 0, stream>>>(h_ln, w1_t, b1 + l * MLPD, nullptr, h_mid, TOK, MLPD, DIM, DIM);
        // MLP2: split-K x2, partials in attn2 region (dead), fused reduce (+bias, += residual)
        gemm_k<3><<<dim3(50, 3, 2), B512, 0, stream>>>(h_mid, w2_t, nullptr, part_m2, nullptr,
                                                       TOK, DIM, MLPD, MLPD / 2);
        redk_k<<<2048, B256, 0, stream>>>(xbuf, part_m2, b2 + l * DIM);
    }

    ln_k<<<BATCH, B256, 0, stream>>>(xbuf, (long)SEQ * DIM, lnf_g, lnf_b, h_ln);
    gemm_h<<<dim3(1, 8), B256, 0, stream>>>(h_ln, wt_head, b_head, out, BATCH, FEAT, DIM);
}

// Round 14
// 1746.850 us; speedup vs baseline: 1.6004x; 1.0278x over previous
//
#include <hip/hip_runtime.h>
#include <cstdint>

typedef __bf16 bf16_t;
typedef __bf16 bf16x8 __attribute__((ext_vector_type(8)));
typedef float  f32x4  __attribute__((ext_vector_type(4)));
typedef unsigned int u32;

#define DEPTH 6
#define HEADS 12
#define DH    64
#define DIM   768
#define MLPD  3072
#define FEAT  1000
#define BATCH 32
#define SEQ   197
#define NP    224          // padded j stride for attention matrices
#define TOK   (BATCH*SEQ)  // 6304

__device__ __forceinline__ f32x4 zero4() {
    f32x4 z; z[0] = 0.f; z[1] = 0.f; z[2] = 0.f; z[3] = 0.f; return z;
}

__device__ __forceinline__ f32x4 mfma16(bf16x8 a, bf16x8 b, f32x4 c) {
    return __builtin_amdgcn_mfma_f32_16x16x32_bf16(a, b, c, 0, 0, 0);
}

// async global->LDS, 16B per lane. lds base must be wave-uniform; HW adds lane*16.
typedef const __attribute__((address_space(1))) u32* gas_ptr;
typedef __attribute__((address_space(3))) u32*       las_ptr;
__device__ __forceinline__ void gload16(const bf16_t* g, bf16_t* l) {
    __builtin_amdgcn_global_load_lds((gas_ptr)g, (las_ptr)l, 16, 0, 0);
}

// ---------------- concat cls + x -> xbuf ----------------
__global__ __launch_bounds__(256) void concat_k(const float* __restrict__ x,
                                                const float* __restrict__ cls,
                                                float* __restrict__ xbuf) {
    int idx = blockIdx.x * 256 + threadIdx.x;      // exactly 6304*768 threads
    int col = idx % DIM;
    int row = idx / DIM;
    int b = row / SEQ, p = row % SEQ;
    xbuf[idx] = (p == 0) ? cls[col] : x[(b * 196 + p - 1) * DIM + col];
}

// ---------------- transpose + fp32->bf16:  W[K][N] -> Wt[N][K] (head only) ----------------
__global__ __launch_bounds__(256) void tcvt_k(const float* __restrict__ W,
                                              bf16_t* __restrict__ Wt,
                                              int K, int N) {
    __shared__ float t[32][33];
    int n0 = blockIdx.x * 32, k0 = blockIdx.y * 32;
    int c = threadIdx.x & 31, r = threadIdx.x >> 5;
#pragma unroll
    for (int i = 0; i < 4; i++) {
        int k = k0 + r + i * 8, n = n0 + c;
        t[r + i * 8][c] = (n < N) ? W[k * N + n] : 0.f;
    }
    __syncthreads();
#pragma unroll
    for (int i = 0; i < 4; i++) {
        int n = n0 + r + i * 8, k = k0 + c;
        if (n < N) Wt[n * K + k] = (bf16_t)t[c][r + i * 8];
    }
}

// ------- batched transpose+convert of one layer's 4 weights in a single dispatch -------
__global__ __launch_bounds__(256) void tcvtall_k(const float* __restrict__ wq,
                                                 const float* __restrict__ wo,
                                                 const float* __restrict__ w1p,
                                                 const float* __restrict__ w2p,
                                                 bf16_t* __restrict__ wt) {
    int id = blockIdx.x;
    const float* W; int K, N, ntx, rid; long doff;
    if (id < 1728)      { W = wq;  K = 768;  N = 2304; doff = 0;       ntx = 72; rid = id; }
    else if (id < 2304) { W = wo;  K = 768;  N = 768;  doff = 1769472; ntx = 24; rid = id - 1728; }
    else if (id < 4608) { W = w1p; K = 768;  N = 3072; doff = 2359296; ntx = 96; rid = id - 2304; }
    else                { W = w2p; K = 3072; N = 768;  doff = 4718592; ntx = 24; rid = id - 4608; }
    int n0 = (rid % ntx) * 32, k0 = (rid / ntx) * 32;
    __shared__ float t[32][33];
    int c = threadIdx.x & 31, r = threadIdx.x >> 5;
#pragma unroll
    for (int i = 0; i < 4; i++)
        t[r + i * 8][c] = W[(long)(k0 + r + i * 8) * N + n0 + c];
    __syncthreads();
#pragma unroll
    for (int i = 0; i < 4; i++)
        wt[doff + (long)(n0 + r + i * 8) * K + k0 + c] = (bf16_t)t[c][r + i * 8];
}

// ---------------- row LayerNorm over 768 cols, fp32 in -> bf16 out ----------------
__global__ __launch_bounds__(256) void ln_k(const float* __restrict__ x, long row_stride,
                                            const float* __restrict__ g,
                                            const float* __restrict__ b,
                                            bf16_t* __restrict__ out) {
    int row = blockIdx.x;
    const float* xr = x + (long)row * row_stride;
    int t = threadIdx.x;
    float v0 = xr[t], v1 = xr[t + 256], v2 = xr[t + 512];
    float s  = v0 + v1 + v2;
    float sq = v0 * v0 + v1 * v1 + v2 * v2;
#pragma unroll
    for (int o = 1; o < 64; o <<= 1) { s += __shfl_xor(s, o); sq += __shfl_xor(sq, o); }
    __shared__ float ss[4], sqs[4];
    int w = t >> 6;
    if ((t & 63) == 0) { ss[w] = s; sqs[w] = sq; }
    __syncthreads();
    s  = ss[0] + ss[1] + ss[2] + ss[3];
    sq = sqs[0] + sqs[1] + sqs[2] + sqs[3];
    float m  = s * (1.f / 768.f);
    float rs = rsqrtf(sq * (1.f / 768.f) - m * m + 1e-5f);
    bf16_t* orow = out + (long)row * DIM;
    orow[t]       = (bf16_t)((v0 - m) * rs * g[t]       + b[t]);
    orow[t + 256] = (bf16_t)((v1 - m) * rs * g[t + 256] + b[t + 256]);
    orow[t + 512] = (bf16_t)((v2 - m) * rs * g[t + 512] + b[t + 512]);
}

// ====== big GEMM: r3 schedule widened to 128x256, 512 thr / 8 waves (2m x 4n) ======
// MODE 0: Cb=acc; 1: Cf+=acc+bias; 2: Cb=gelu(acc+bias); 3: Cf[kc*M*N+..]=acc (split-K)
template <int MODE>
__global__ __launch_bounds__(512) void gemm_k(const bf16_t* __restrict__ A,
                                              const bf16_t* __restrict__ Bt,
                                              const float* __restrict__ bias,
                                              float* __restrict__ Cf,
                                              bf16_t* __restrict__ Cb,
                                              int M, int N, int Kstride, int Klen) {
    __shared__ bf16_t sA[2][128][32];   // 16 KB
    __shared__ bf16_t sB[2][256][32];   // 32 KB
    int tid = threadIdx.x;
    int bm = blockIdx.x * 128, bn = blockIdx.y * 256;
    long koff = (long)blockIdx.z * Klen;
    int wave = tid >> 6, lane = tid & 63;
    int wm = (wave >> 2) * 64, wn = (wave & 3) * 64;
    int la = lane & 15, lb = lane >> 4;

    int trow = tid >> 2, colE = (tid & 3) * 8;
    int rowA = bm + trow; if (rowA > M - 1) rowA = M - 1;
    int rowB0 = bn + trow, rowB1 = bn + 128 + trow;   // N multiple of 256

    f32x4 acc[4][4];
#pragma unroll
    for (int m = 0; m < 4; m++)
#pragma unroll
        for (int n = 0; n < 4; n++) acc[m][n] = zero4();

    auto stage = [&](int buf, long k0) {
        gload16(A  + (long)rowA  * Kstride + k0 + colE, &sA[buf][0][0] + wave * 512);
        gload16(Bt + (long)rowB0 * Kstride + k0 + colE, &sB[buf][0][0] + wave * 512);
        gload16(Bt + (long)rowB1 * Kstride + k0 + colE, &sB[buf][0][0] + 4096 + wave * 512);
    };

    int nt = Klen >> 5;
    stage(0, koff);
    __syncthreads();
    for (int t = 0; t < nt; t++) {
        int cur = t & 1;
        if (t + 1 < nt) stage(cur ^ 1, koff + ((long)(t + 1) << 5));
        bf16x8 af[4], bfr[4];
#pragma unroll
        for (int m = 0; m < 4; m++) af[m]  = *(const bf16x8*)&sA[cur][wm + m * 16 + la][lb * 8];
#pragma unroll
        for (int n = 0; n < 4; n++) bfr[n] = *(const bf16x8*)&sB[cur][wn + n * 16 + la][lb * 8];
#pragma unroll
        for (int m = 0; m < 4; m++)
#pragma unroll
            for (int n = 0; n < 4; n++)
                acc[m][n] = mfma16(af[m], bfr[n], acc[m][n]);
        __syncthreads();   // implicit vmcnt(0): publishes next buf + protects cur
    }

    long kout = (long)blockIdx.z * M * (long)N;   // split-K output chunk offset
#pragma unroll
    for (int m = 0; m < 4; m++) {
#pragma unroll
        for (int n = 0; n < 4; n++) {
            int ib = bm + wm + m * 16 + lb * 4;
            int jb = bn + wn + n * 16 + la;       // < N always (N mult of 256)
            float bv = (MODE == 1 || MODE == 2) ? bias[jb] : 0.f;
#pragma unroll
            for (int r = 0; r < 4; r++) {
                int i = ib + r;
                if (i >= M) continue;
                float v = acc[m][n][r];
                if (MODE == 0) {
                    Cb[(long)i * N + jb] = (bf16_t)v;
                } else if (MODE == 1) {
                    Cf[(long)i * N + jb] += v + bv;
                } else if (MODE == 2) {
                    float u = v + bv;
                    Cb[(long)i * N + jb] = (bf16_t)(0.5f * u * (1.f + erff(u * 0.70710678118f)));
                } else {
                    Cf[kout + (long)i * N + jb] = v;
                }
            }
        }
    }
}

// ----- fused split-K reduce (+bias, += residual) and optional row-LayerNorm -----
// one block per row; NC partial chunks; residual row stays in registers for the LN.
template <int NC, bool DOLN>
__global__ __launch_bounds__(256) void redln_k(float* __restrict__ xbuf,
                                               const float* __restrict__ part,
                                               const float* __restrict__ bias,
                                               const float* __restrict__ g,
                                               const float* __restrict__ b,
                                               bf16_t* __restrict__ out) {
    int row = blockIdx.x, t = threadIdx.x;
    long base = (long)row * DIM;
    const long total = (long)TOK * DIM;
    float v[3];
    float s = 0.f, sq = 0.f;
#pragma unroll
    for (int q = 0; q < 3; q++) {
        int col = t + q * 256;
        long idx = base + col;
        float val = xbuf[idx] + bias[col];
#pragma unroll
        for (int k = 0; k < NC; k++) val += part[idx + (long)k * total];
        xbuf[idx] = val;
        v[q] = val; s += val; sq += val * val;
    }
    if (DOLN) {
#pragma unroll
        for (int o = 1; o < 64; o <<= 1) { s += __shfl_xor(s, o); sq += __shfl_xor(sq, o); }
        __shared__ float ss[4], sqs[4];
        int w = t >> 6;
        if ((t & 63) == 0) { ss[w] = s; sqs[w] = sq; }
        __syncthreads();
        s  = ss[0] + ss[1] + ss[2] + ss[3];
        sq = sqs[0] + sqs[1] + sqs[2] + sqs[3];
        float m  = s * (1.f / 768.f);
        float rs = rsqrtf(sq * (1.f / 768.f) - m * m + 1e-5f);
        bf16_t* orow = out + base;
#pragma unroll
        for (int q = 0; q < 3; q++) {
            int col = t + q * 256;
            orow[col] = (bf16_t)((v[q] - m) * rs * g[col] + b[col]);
        }
    }
}

// ---------------- head GEMM: 128x128, 2-phase dbuf (tiny, M=32) ----------------
__global__ __launch_bounds__(256) void gemm_h(const bf16_t* __restrict__ A,
                                              const bf16_t* __restrict__ Bt,
                                              const float* __restrict__ bias,
                                              float* __restrict__ Cf,
                                              int M, int N, int K) {
    __shared__ bf16_t sA[2][128][32];
    __shared__ bf16_t sB[2][128][32];
    int tid = threadIdx.x;
    int bm = blockIdx.x * 128, bn = blockIdx.y * 128;
    int wave = tid >> 6, lane = tid & 63;
    int wm = (wave >> 1) * 64, wn = (wave & 1) * 64;
    int la = lane & 15, lb = lane >> 4;
    int rowA[2], rowB[2], colE[2];
#pragma unroll
    for (int q = 0; q < 2; q++) {
        int li = (wave * 2 + q) * 64 + lane;
        int row = li >> 2;
        colE[q] = (li & 3) * 8;
        int ar = bm + row; if (ar > M - 1) ar = M - 1;
        int br = bn + row; if (br > N - 1) br = N - 1;
        rowA[q] = ar; rowB[q] = br;
    }
    f32x4 acc[4][4];
#pragma unroll
    for (int m = 0; m < 4; m++)
#pragma unroll
        for (int n = 0; n < 4; n++) acc[m][n] = zero4();
    int nt = K >> 5;
#pragma unroll
    for (int q = 0; q < 2; q++) {
        gload16(A  + (long)rowA[q] * K + colE[q], &sA[0][0][0] + (wave * 2 + q) * 512);
        gload16(Bt + (long)rowB[q] * K + colE[q], &sB[0][0][0] + (wave * 2 + q) * 512);
    }
    __syncthreads();
    for (int t = 0; t < nt; t++) {
        int cur = t & 1;
        if (t + 1 < nt) {
            int k0 = (t + 1) << 5;
#pragma unroll
            for (int q = 0; q < 2; q++) {
                gload16(A  + (long)rowA[q] * K + k0 + colE[q], &sA[cur ^ 1][0][0] + (wave * 2 + q) * 512);
                gload16(Bt + (long)rowB[q] * K + k0 + colE[q], &sB[cur ^ 1][0][0] + (wave * 2 + q) * 512);
            }
        }
        bf16x8 af[4], bfr[4];
#pragma unroll
        for (int m = 0; m < 4; m++) af[m]  = *(const bf16x8*)&sA[cur][wm + m * 16 + la][lb * 8];
#pragma unroll
        for (int n = 0; n < 4; n++) bfr[n] = *(const bf16x8*)&sB[cur][wn + n * 16 + la][lb * 8];
#pragma unroll
        for (int m = 0; m < 4; m++)
#pragma unroll
            for (int n = 0; n < 4; n++)
                acc[m][n] = mfma16(af[m], bfr[n], acc[m][n]);
        __syncthreads();
    }
#pragma unroll
    for (int m = 0; m < 4; m++) {
#pragma unroll
        for (int n = 0; n < 4; n++) {
            int ib = bm + wm + m * 16 + lb * 4;
            int jb = bn + wn + n * 16 + la;
            if (jb >= N) continue;
            float bv = bias[jb];
#pragma unroll
            for (int r = 0; r < 4; r++) {
                int i = ib + r;
                if (i >= M) continue;
                Cf[(long)i * N + jb] = acc[m][n][r] + bv;
            }
        }
    }
}

// ---------------- QK^T * scale -> dots (bf16, padded NP) ----------------
__global__ __launch_bounds__(256) void qk_k(const bf16_t* __restrict__ qkv,
                                            bf16_t* __restrict__ dots) {
    int bh = blockIdx.z;
    int b = bh / HEADS, h = bh % HEADS;
    int i0 = blockIdx.x * 64, j0 = blockIdx.y * 64;
    __shared__ bf16_t sQ[64][32], sK[64][32];
    int tid = threadIdx.x, wave = tid >> 6, lane = tid & 63;
    int wm = (wave >> 1) * 32, wn = (wave & 1) * 32;
    int la = lane & 15, lb = lane >> 4;
    f32x4 acc[2][2];
#pragma unroll
    for (int m = 0; m < 2; m++)
#pragma unroll
        for (int n = 0; n < 2; n++) acc[m][n] = zero4();

    int row = tid >> 2, col = (tid & 3) * 8;
    int qi = i0 + row; if (qi > SEQ - 1) qi = SEQ - 1;
    int kj = j0 + row; if (kj > SEQ - 1) kj = SEQ - 1;
    const bf16_t* qsrc = qkv + (((b * SEQ + qi) * 3 + 0) * HEADS + h) * DH + col;
    const bf16_t* ksrc = qkv + (((b * SEQ + kj) * 3 + 1) * HEADS + h) * DH + col;

#pragma unroll
    for (int d0 = 0; d0 < 64; d0 += 32) {
        *(bf16x8*)&sQ[row][col] = *(const bf16x8*)(qsrc + d0);
        *(bf16x8*)&sK[row][col] = *(const bf16x8*)(ksrc + d0);
        __syncthreads();
        bf16x8 af[2], bfr[2];
#pragma unroll
        for (int m = 0; m < 2; m++) af[m]  = *(const bf16x8*)&sQ[wm + m * 16 + la][lb * 8];
#pragma unroll
        for (int n = 0; n < 2; n++) bfr[n] = *(const bf16x8*)&sK[wn + n * 16 + la][lb * 8];
#pragma unroll
        for (int m = 0; m < 2; m++)
#pragma unroll
            for (int n = 0; n < 2; n++)
                acc[m][n] = mfma16(af[m], bfr[n], acc[m][n]);
        __syncthreads();
    }
#pragma unroll
    for (int m = 0; m < 2; m++)
#pragma unroll
        for (int n = 0; n < 2; n++)
#pragma unroll
            for (int r = 0; r < 4; r++) {
                int i = i0 + wm + m * 16 + lb * 4 + r;
                int j = j0 + wn + n * 16 + la;
                if (i < SEQ && j < SEQ)
                    dots[((long)bh * SEQ + i) * NP + j] = (bf16_t)(acc[m][n][r] * 0.125f);
            }
}

// -------- fused softmax + re-attention (head mix + LN) -> attn2 (bf16); bf16 dots --------
__global__ __launch_bounds__(256) void smre_k(const bf16_t* __restrict__ dots,
                                              const float* __restrict__ W,
                                              const float* __restrict__ gg,
                                              const float* __restrict__ bb,
                                              bf16_t* __restrict__ attn2) {
    __shared__ float sm[HEADS][NP];
    __shared__ float sW[HEADS * HEADS];
    __shared__ float sg[HEADS], sb[HEADS];
    int tid = threadIdx.x;
    if (tid < HEADS * HEADS) sW[tid] = W[tid];
    if (tid < HEADS) { sg[tid] = gg[tid]; sb[tid] = bb[tid]; }
    int bi = blockIdx.x;             // b*SEQ + i
    int b = bi / SEQ, i = bi % SEQ;
    int wave = tid >> 6, lane = tid & 63;

    for (int h = wave; h < HEADS; h += 4) {
        const bf16_t* p = dots + ((long)(b * HEADS + h) * SEQ + i) * NP;
        float v[4], e[4];
#pragma unroll
        for (int q = 0; q < 4; q++) { int j = lane + 64 * q; v[q] = (j < SEQ) ? (float)p[j] : -3.0e38f; }
        float mx = fmaxf(fmaxf(v[0], v[1]), fmaxf(v[2], v[3]));
#pragma unroll
        for (int o = 1; o < 64; o <<= 1) mx = fmaxf(mx, __shfl_xor(mx, o));
        float s = 0.f;
#pragma unroll
        for (int q = 0; q < 4; q++) {
            int j = lane + 64 * q;
            e[q] = (j < SEQ) ? __expf(v[q] - mx) : 0.f;
            s += e[q];
        }
#pragma unroll
        for (int o = 1; o < 64; o <<= 1) s += __shfl_xor(s, o);
        float inv = 1.f / s;
#pragma unroll
        for (int q = 0; q < 4; q++) { int j = lane + 64 * q; if (j < NP) sm[h][j] = e[q] * inv; }
    }
    __syncthreads();

    int j = tid;
    if (j >= NP) return;
    bool valid = j < SEQ;
    float vals[HEADS];
#pragma unroll
    for (int h = 0; h < HEADS; h++) vals[h] = valid ? sm[h][j] : 0.f;
    float mix[HEADS];
    float s = 0.f, sq = 0.f;
#pragma unroll
    for (int g = 0; g < HEADS; g++) {
        float a = 0.f;
#pragma unroll
        for (int h = 0; h < HEADS; h++) a += vals[h] * sW[h * HEADS + g];
        mix[g] = a; s += a; sq += a * a;
    }
    float m  = s * (1.f / 12.f);
    float rs = rsqrtf(sq * (1.f / 12.f) - m * m + 1e-5f);
    long base = ((long)(b * HEADS) * SEQ + i) * NP + j;
    const long hs = (long)SEQ * NP;
#pragma unroll
    for (int g = 0; g < HEADS; g++) {
        float o = valid ? ((mix[g] - m) * rs * sg[g] + sb[g]) : 0.f;
        attn2[base + g * hs] = (bf16_t)o;
    }
}

// ---------------- PV: out[b,h,i,d] = sum_j attn2 * v  -> aout[b,i,h*64+d] (bf16) ----------------
__global__ __launch_bounds__(256) void pv_k(const bf16_t* __restrict__ attn2,
                                            const bf16_t* __restrict__ qkv,
                                            bf16_t* __restrict__ aout) {
    int bh = blockIdx.y;
    int b = bh / HEADS, h = bh % HEADS;
    int i0 = blockIdx.x * 64;
    __shared__ bf16_t sP[64][32];
    __shared__ bf16_t sVt[64][32];   // logical [d][j], XOR-swizzled on j-blocks
    int tid = threadIdx.x, wave = tid >> 6, lane = tid & 63;
    int wm = (wave >> 1) * 32, wn = (wave & 1) * 32;
    int la = lane & 15, lb = lane >> 4;
    f32x4 acc[2][2];
#pragma unroll
    for (int m = 0; m < 2; m++)
#pragma unroll
        for (int n = 0; n < 2; n++) acc[m][n] = zero4();

    int prow = tid >> 2, pcol = (tid & 3) * 8;
    int pi = i0 + prow; if (pi > SEQ - 1) pi = SEQ - 1;
    const bf16_t* psrc = attn2 + ((long)bh * SEQ + pi) * NP + pcol;
    int jl = tid >> 3, dblk = (tid & 7) * 8;
    int jlx = jl ^ ((tid & 3) << 3);

    for (int j0 = 0; j0 < NP; j0 += 32) {
        *(bf16x8*)&sP[prow][pcol] = *(const bf16x8*)(psrc + j0);
        int jg = j0 + jl;
        bf16x8 vv;
#pragma unroll
        for (int e = 0; e < 8; e++) vv[e] = (bf16_t)0.f;
        if (jg < SEQ)
            vv = *(const bf16x8*)(qkv + (((b * SEQ + jg) * 3 + 2) * HEADS + h) * DH + dblk);
#pragma unroll
        for (int e = 0; e < 8; e++) sVt[dblk + e][jlx] = vv[e];
        __syncthreads();
        bf16x8 af[2], bfr[2];
#pragma unroll
        for (int m = 0; m < 2; m++) af[m] = *(const bf16x8*)&sP[wm + m * 16 + la][lb * 8];
#pragma unroll
        for (int n = 0; n < 2; n++) {
            int rowd = wn + n * 16 + la;
            int colj = (lb * 8) ^ (((rowd >> 3) & 3) << 3);
            bfr[n] = *(const bf16x8*)&sVt[rowd][colj];
        }
#pragma unroll
        for (int m = 0; m < 2; m++)
#pragma unroll
            for (int n = 0; n < 2; n++)
                acc[m][n] = mfma16(af[m], bfr[n], acc[m][n]);
        __syncthreads();
    }
#pragma unroll
    for (int m = 0; m < 2; m++)
#pragma unroll
        for (int n = 0; n < 2; n++)
#pragma unroll
            for (int r = 0; r < 4; r++) {
                int i = i0 + wm + m * 16 + lb * 4 + r;
                int d = wn + n * 16 + la;
                if (i < SEQ)
                    aout[((long)b * SEQ + i) * DIM + h * DH + d] = (bf16_t)acc[m][n][r];
            }
}

// ---------------- host orchestration ----------------
extern "C" void kernel_launch(void* const* d_in, const int* in_sizes, int n_in,
                              void* d_out, int out_size, void* d_ws, size_t ws_size,
                              hipStream_t stream) {
    const float* x        = (const float*)d_in[0];
    const float* cls      = (const float*)d_in[1];
    const float* ln1_g    = (const float*)d_in[2];
    const float* ln1_b    = (const float*)d_in[3];
    const float* w_qkv    = (const float*)d_in[4];
    const float* reattn_w = (const float*)d_in[5];
    const float* reattn_g = (const float*)d_in[6];
    const float* reattn_b = (const float*)d_in[7];
    const float* w_out    = (const float*)d_in[8];
    const float* b_out    = (const float*)d_in[9];
    const float* ln2_g    = (const float*)d_in[10];
    const float* ln2_b    = (const float*)d_in[11];
    const float* w1       = (const float*)d_in[12];
    const float* b1       = (const float*)d_in[13];
    const float* w2       = (const float*)d_in[14];
    const float* b2       = (const float*)d_in[15];
    const float* lnf_g    = (const float*)d_in[16];
    const float* lnf_b    = (const float*)d_in[17];
    const float* w_head   = (const float*)d_in[18];
    const float* b_head   = (const float*)d_in[19];
    float* out = (float*)d_out;

    char* p = (char*)d_ws;
    auto alloc = [&](size_t bytes) -> char* {
        char* r = p;
        p += (bytes + 255) & ~(size_t)255;
        return r;
    };
    bf16_t* wt      = (bf16_t*)alloc(2ULL * 7077888);              // all 4 layer weights, transposed
    bf16_t* wt_head = (bf16_t*)alloc(2ULL * FEAT * DIM);
    float*  xbuf    = (float*)alloc(4ULL * TOK * DIM);
    bf16_t* h_ln    = (bf16_t*)alloc(2ULL * TOK * DIM);
    bf16_t* qkv     = (bf16_t*)alloc(2ULL * TOK * 3 * DIM);
    // dots region: 38.7 MB = max(bf16 dots 33.9, h_mid 38.7, OP partials 2x19.4)
    char*   dreg    = alloc(2ULL * TOK * MLPD);
    bf16_t* dots    = (bf16_t*)dreg;
    bf16_t* h_mid   = (bf16_t*)dreg;
    float*  part_op = (float*)dreg;
    // attn2(33.9) + aout(9.7) + ext(33.9) are exactly contiguous (all sizes 256-mult)
    // and span exactly 4 split-K chunks (4 x 19.37 MB) for MLP2.
    bf16_t* attn2   = (bf16_t*)alloc(2ULL * BATCH * HEADS * SEQ * NP);
    bf16_t* aout    = (bf16_t*)alloc(2ULL * TOK * DIM);
    alloc(4ULL * 4 * TOK * DIM - 2ULL * BATCH * HEADS * SEQ * NP - 2ULL * TOK * DIM);
    float*  part_m2 = (float*)attn2;
    // Safety: attn2 dead after pv_k; aout dead after OP gemm; dots dead after smre_k;
    // h_mid written only at MLP1 (after redln consumed part_op). All per-use verified.

    dim3 B256(256), B512(512);
    concat_k<<<(TOK * DIM) / 256, B256, 0, stream>>>(x, cls, xbuf);
    tcvt_k<<<dim3((FEAT + 31) / 32, DIM / 32), B256, 0, stream>>>(w_head, wt_head, DIM, FEAT);

    bf16_t* wqkv_t = wt;                 // [2304][768]
    bf16_t* wout_t = wt + 1769472;       // [768][768]
    bf16_t* w1_t   = wt + 2359296;       // [3072][768]
    bf16_t* w2_t   = wt + 4718592;       // [768][3072]

    ln_k<<<TOK, B256, 0, stream>>>(xbuf, DIM, ln1_g, ln1_b, h_ln);   // ln1, layer 0

    for (int l = 0; l < DEPTH; l++) {
        tcvtall_k<<<6912, B256, 0, stream>>>(w_qkv + (long)l * DIM * 2304,
                                             w_out + (long)l * DIM * DIM,
                                             w1 + (long)l * DIM * MLPD,
                                             w2 + (long)l * MLPD * DIM, wt);
        gemm_k<0><<<dim3(50, 9), B512, 0, stream>>>(h_ln, wqkv_t, nullptr, nullptr, qkv, TOK, 2304, DIM, DIM);
        qk_k<<<dim3(4, 4, BATCH * HEADS), B256, 0, stream>>>(qkv, dots);
        smre_k<<<TOK, B256, 0, stream>>>(
            dots, reattn_w + l * HEADS * HEADS, reattn_g + l * HEADS, reattn_b + l * HEADS, attn2);
        pv_k<<<dim3(4, BATCH * HEADS), B256, 0, stream>>>(attn2, qkv, aout);
        // OP: split-K x2, partials in dots region (dead); fused reduce+ln2 -> h_ln
        gemm_k<3><<<dim3(50, 3, 2), B512, 0, stream>>>(aout, wout_t, nullptr, part_op, nullptr,
                                                       TOK, DIM, DIM, DIM / 2);
        redln_k<2, true><<<TOK, B256, 0, stream>>>(xbuf, part_op, b_out + l * DIM,
                                                   ln2_g + l * DIM, ln2_b + l * DIM, h_ln);
        gemm_k<2><<<dim3(50, 12), B512, 0, stream>>>(h_ln, w1_t, b1 + l * MLPD, nullptr, h_mid, TOK, MLPD, DIM, DIM);
        // MLP2: split-K x4, partials across attn2+aout+ext; fused reduce+ln1(l+1)
        gemm_k<3><<<dim3(50, 3, 4), B512, 0, stream>>>(h_mid, w2_t, nullptr, part_m2, nullptr,
                                                       TOK, DIM, MLPD, MLPD / 4);
        if (l < DEPTH - 1)
            redln_k<4, true><<<TOK, B256, 0, stream>>>(xbuf, part_m2, b2 + l * DIM,
                                                       ln1_g + (l + 1) * DIM, ln1_b + (l + 1) * DIM, h_ln);
        else
            redln_k<4, false><<<TOK, B256, 0, stream>>>(xbuf, part_m2, b2 + l * DIM,
                                                        nullptr, nullptr, nullptr);
    }

    ln_k<<<BATCH, B256, 0, stream>>>(xbuf, (long)SEQ * DIM, lnf_g, lnf_b, h_ln);
    gemm_h<<<dim3(1, 8), B256, 0, stream>>>(h_ln, wt_head, b_head, out, BATCH, FEAT, DIM);
}